// Round 11
// baseline (154.214 us; speedup 1.0000x reference)
//
#include <hip/hip_runtime.h>
#include <hip/hip_bf16.h>
#include <stdint.h>

#define NN 2048
#define DD 1024
#define HH 16
#define HDD 64
#define KVBLK 64

typedef unsigned short u16;
typedef __attribute__((ext_vector_type(8))) __bf16 bf16x8_t;
typedef __attribute__((ext_vector_type(4))) float f32x4_t;

#define LOG2E 1.44269504f

static __device__ __forceinline__ u16 f2bf(float f) {
  union { float f; uint32_t u; } v; v.f = f;
  uint32_t r = v.u + 0x7FFFu + ((v.u >> 16) & 1u);
  return (u16)(r >> 16);
}

static __device__ __forceinline__ uint32_t packbf2(float a, float b) {
  __hip_bfloat162 h2 = __float22bfloat162_rn(make_float2(a, b));
  union { __hip_bfloat162 hh; uint32_t u; } cvt; cvt.hh = h2;
  return cvt.u;
}

// async global->LDS, 16B per lane. LDS dest must be wave-uniform base + lane*16.
static __device__ __forceinline__ void async_copy16(const void* g, void* l) {
  __builtin_amdgcn_global_load_lds((const __attribute__((address_space(1))) void*)g,
                                   (__attribute__((address_space(3))) void*)l, 16, 0, 0);
}

// ---------------- weight transpose+cast: Wt[n][k] = W[k][n], 4 weights in one launch ----------------
__global__ void transpose_w_kernel(const float* __restrict__ W0, const float* __restrict__ W1,
                                   const float* __restrict__ W2, const float* __restrict__ W3,
                                   u16* __restrict__ Wt) {
  __shared__ float tile[64][65];
  const float* W = blockIdx.y == 0 ? W0 : blockIdx.y == 1 ? W1 : blockIdx.y == 2 ? W2 : W3;
  u16* out = Wt + (size_t)blockIdx.y * DD * DD;
  int bx = blockIdx.x & 15;   // n tile
  int by = blockIdx.x >> 4;   // k tile
  int t = threadIdx.x;
  int c = t & 63, r4 = t >> 6;
#pragma unroll
  for (int i = 0; i < 16; i++) {
    int row = i * 4 + r4;
    tile[row][c] = W[(by * 64 + row) * DD + bx * 64 + c];
  }
  __syncthreads();
#pragma unroll
  for (int i = 0; i < 16; i++) {
    int row = i * 4 + r4;
    out[(bx * 64 + row) * DD + by * 64 + c] = f2bf(tile[c][row]);
  }
}

// ---------------- log-sigmoid gate + fused x->bf16 cast ----------------
__global__ void logf_kernel(const float* __restrict__ x, const float* __restrict__ Wf,
                            float* __restrict__ lf, u16* __restrict__ xb) {
  __shared__ float xs[DD];
  __shared__ float part[16][17];
  int row = blockIdx.x;   // b*N + n
  int t = threadIdx.x;    // 256
  float4 v = *(const float4*)&x[(size_t)row * DD + t * 4];
  *(float4*)&xs[t * 4] = v;
  ushort4 o;
  o.x = f2bf(v.x); o.y = f2bf(v.y); o.z = f2bf(v.z); o.w = f2bf(v.w);
  *(ushort4*)&xb[(size_t)row * DD + t * 4] = o;
  __syncthreads();
  int h = t & 15, chunk = t >> 4;
  float s = 0.f;
#pragma unroll 8
  for (int e = 0; e < 64; e++)
    s += xs[chunk * 64 + e] * Wf[(chunk * 64 + e) * HH + h];
  part[chunk][h] = s;
  __syncthreads();
  if (t < 16) {
    float z = 0.f;
#pragma unroll
    for (int i = 0; i < 16; i++) z += part[i][t];
    float ls = fminf(z, 0.f) - log1pf(__expf(-fabsf(z)));
    int b = row >> 11, n = row & (NN - 1);
    lf[(b * HH + t) * NN + n] = ls;
  }
}

// ---------------- cumsum over n per (b,h): float4/lane; output pre-scaled by log2(e) ----------------
__global__ void cumsum_kernel(const float* __restrict__ lf, float* __restrict__ c) {
  int bh = blockIdx.x;
  int lane = threadIdx.x;  // 64
  const float* in = lf + bh * NN;
  float* out = c + bh * NN;
  float carry = 0.f;
  for (int t0 = 0; t0 < NN; t0 += 256) {
    float4 v = *(const float4*)&in[t0 + lane * 4];
    float s1 = v.x + v.y, s2 = s1 + v.z, s3 = s2 + v.w;
    float incl = s3;
#pragma unroll
    for (int off = 1; off < 64; off <<= 1) {
      float u = __shfl_up(incl, off, 64);
      if (lane >= off) incl += u;
    }
    float excl = incl - s3 + carry;
    float4 o;
    o.x = (excl + v.x) * LOG2E; o.y = (excl + s1) * LOG2E;
    o.z = (excl + s2) * LOG2E; o.w = (excl + s3) * LOG2E;
    *(float4*)&out[t0 + lane * 4] = o;
    carry = __shfl(incl, 63, 64) + carry;
  }
}

// ---------------- GEMM 128x128 tile, BK=64, swizzled LDS, 512 threads (8 waves, 2x4) ----------------
// mode 0 (QKV fused): Wt is [3072][1024]; n-range selects oQ/oK/oV, bf16 [bh][n][hd]
// mode 1 (output):    Wt is [1024][1024]; fp32 flat to oF
__global__ __launch_bounds__(512, 4) void gemm_kernel(const u16* __restrict__ A,
                                                      const u16* __restrict__ Wt,
                                                      u16* __restrict__ oQ, u16* __restrict__ oK,
                                                      u16* __restrict__ oV, float* __restrict__ oF,
                                                      int mode) {
  __shared__ u16 Als[128 * 64];
  __shared__ u16 Bls[128 * 64];
  int m0 = blockIdx.y * 128, n0 = blockIdx.x * 128;
  int tid = threadIdx.x;
  int lane = tid & 63, w = tid >> 6;   // 8 waves
  int wm = w >> 2, wn = w & 3;         // 2 x 4 wave grid: 64 rows x 32 cols each
  int lr = lane & 15, lg = lane >> 4;

  const u16* gA[2]; const u16* gB[2]; u16* lA[2]; u16* lB[2];
#pragma unroll
  for (int j = 0; j < 2; j++) {
    int s = tid + j * 512;
    int row = s >> 3, ch = s & 7;
    int scol = (ch ^ (row & 7)) * 8;
    gA[j] = &A [(size_t)(m0 + row) * DD + scol];
    gB[j] = &Wt[(size_t)(n0 + row) * DD + scol];
    lA[j] = &Als[s * 8];
    lB[j] = &Bls[s * 8];
  }

  f32x4_t acc[4][2];
#pragma unroll
  for (int i = 0; i < 4; i++)
#pragma unroll
    for (int j = 0; j < 2; j++) acc[i][j] = (f32x4_t){0.f, 0.f, 0.f, 0.f};

  for (int kt = 0; kt < DD; kt += 64) {
    __syncthreads();
#pragma unroll
    for (int j = 0; j < 2; j++) {
      async_copy16(gA[j] + kt, lA[j]);
      async_copy16(gB[j] + kt, lB[j]);
    }
    __syncthreads();
#pragma unroll
    for (int kk = 0; kk < 2; kk++) {
      bf16x8_t af[4], bfv[2];
#pragma unroll
      for (int mi = 0; mi < 4; mi++) {
        int row = wm * 64 + mi * 16 + lr;
        int boff = (row * 128 + kk * 64 + lg * 16) ^ ((row & 7) << 4);
        af[mi] = *(const bf16x8_t*)((const char*)Als + boff);
      }
#pragma unroll
      for (int ni = 0; ni < 2; ni++) {
        int row = wn * 32 + ni * 16 + lr;
        int boff = (row * 128 + kk * 64 + lg * 16) ^ ((row & 7) << 4);
        bfv[ni] = *(const bf16x8_t*)((const char*)Bls + boff);
      }
#pragma unroll
      for (int mi = 0; mi < 4; mi++)
#pragma unroll
        for (int ni = 0; ni < 2; ni++)
          acc[mi][ni] = __builtin_amdgcn_mfma_f32_16x16x32_bf16(af[mi], bfv[ni], acc[mi][ni], 0, 0, 0);
    }
  }

  if (mode == 1) {
#pragma unroll
    for (int mi = 0; mi < 4; mi++)
#pragma unroll
      for (int ni = 0; ni < 2; ni++) {
        int gcol = n0 + wn * 32 + ni * 16 + lr;
#pragma unroll
        for (int r = 0; r < 4; r++) {
          int grow = m0 + wm * 64 + mi * 16 + lg * 4 + r;
          oF[(size_t)grow * DD + gcol] = acc[mi][ni][r];
        }
      }
  } else {
    int which = n0 >> 10;
    u16* outp = which == 0 ? oQ : which == 1 ? oK : oV;
    int nl0 = n0 & 1023;
#pragma unroll
    for (int mi = 0; mi < 4; mi++)
#pragma unroll
      for (int ni = 0; ni < 2; ni++) {
        int gcol = nl0 + wn * 32 + ni * 16 + lr;
        int h = gcol >> 6, hd = gcol & 63;
#pragma unroll
        for (int r = 0; r < 4; r++) {
          int grow = m0 + wm * 64 + mi * 16 + lg * 4 + r;
          int b = grow >> 11, n = grow & (NN - 1);
          outp[((size_t)(b * HH + h) * NN + n) * HDD + hd] = f2bf(acc[mi][ni][r]);
        }
      }
  }
}

// ---------------- V transpose: [bh][n][hd] -> [bh][hd][n] ----------------
__global__ void transpose_v_kernel(const u16* __restrict__ Vtmp, u16* __restrict__ Vt) {
  __shared__ u16 tile[64][80];
  int bh = blockIdx.y;
  int n0 = blockIdx.x * 64;
  int t = threadIdx.x;
  const u16* src = Vtmp + (size_t)bh * NN * HDD;
  u16* dst = Vt + (size_t)bh * HDD * NN;
#pragma unroll
  for (int it = 0; it < 2; it++) {
    int cc = t + it * 256;
    int row = cc >> 3, p = cc & 7;
    *(uint4*)&tile[row][p * 8] = *(const uint4*)&src[(size_t)(n0 + row) * HDD + p * 8];
  }
  __syncthreads();
#pragma unroll
  for (int it = 0; it < 2; it++) {
    int cc = t + it * 256;
    int row = cc >> 3, p = cc & 7;
    union { u16 v[8]; uint4 q; } tmp;
#pragma unroll
    for (int e = 0; e < 8; e++) tmp.v[e] = tile[p * 8 + e][row];
    *(uint4*)&dst[(size_t)row * NN + n0 + p * 8] = tmp.q;
  }
}

// ---------------- flash attention: 32 q-rows/wave (2 groups), 4-wave blocks ----------------
// Each K/V fragment read feeds 2 MFMA (one per q-group); 2 independent softmax chains
// give in-wave ILP. Supertile = 128 q-rows/block; heavy blocks (0..255) dispatched first,
// light complements (256..511) pair to 34 iter-units per CU under round-robin dispatch.
// bh = 4*xcd + j keeps K/V XCD-local (round-7 win). Fixed-max softmax in exp2 domain
// (cw pre-scaled by log2e). Swapped QK^T + permlane P-in-reg (round-8 proven body).
__global__ __launch_bounds__(256, 2) void attn_kernel(const u16* __restrict__ Q,
                                                      const u16* __restrict__ K,
                                                      const u16* __restrict__ Vt,
                                                      const float* __restrict__ cw,
                                                      u16* __restrict__ O) {
  __shared__ u16 Kls[2][KVBLK * 64];
  __shared__ u16 Vls[2][64 * KVBLK];
  int flat = blockIdx.x;            // 512
  int x = flat & 7;                 // XCD under round-robin dispatch
  int i = flat >> 3;                // 0..63
  int half = i >> 5;                // 0 = heavy, 1 = light
  int j = i & 31;
  int bh = x * 4 + (j & 3);
  int th = j >> 2;                  // 0..7
  int tile = half ? th : (15 - th); // supertile index, 0..15 (128 rows each)
  int tid = threadIdx.x;
  int lane = tid & 63, w = tid >> 6;
  int lr = lane & 15, lg = lane >> 4;
  const u16* Qh = Q + (size_t)bh * NN * HDD;
  const u16* Kh = K + (size_t)bh * NN * HDD;
  const u16* Vh = Vt + (size_t)bh * HDD * NN;
  const float* ch = cw + bh * NN;   // pre-scaled by log2e
  int b = bh >> 4, h = bh & 15;

  int qb = tile * 128 + w * 32;     // wave's 32 q-rows: [qb, qb+32)
  int iq0 = qb + lr, iq1 = qb + 16 + lr;
  int tdiag = qb >> 6;              // kv tile containing this wave's diagonal
  int ntiles = 2 * tile + 2;        // block-level kv tiles

  // staging: 512 slots of 16B per 8KB tile; LDS linear at slot*16B;
  // swizzle folded into SOURCE chunk: chunk ^ (row&7).
  int s0 = tid, s1 = tid + 256;
  int r0 = s0 >> 3, p0 = s0 & 7;
  int r1 = s1 >> 3, p1 = s1 & 7;
  const u16* gk0 = &Kh[(size_t)r0 * HDD + ((p0 ^ (r0 & 7)) * 8)];
  const u16* gk1 = &Kh[(size_t)r1 * HDD + ((p1 ^ (r1 & 7)) * 8)];
  const u16* gv0 = &Vh[(size_t)r0 * NN + ((p0 ^ (r0 & 7)) * 8)];
  const u16* gv1 = &Vh[(size_t)r1 * NN + ((p1 ^ (r1 & 7)) * 8)];

  bf16x8_t qf0[2], qf1[2];
#pragma unroll
  for (int s = 0; s < 2; s++) {
    qf0[s] = *(const bf16x8_t*)&Qh[(size_t)iq0 * HDD + s * 32 + lg * 8];
    qf1[s] = *(const bf16x8_t*)&Qh[(size_t)iq1 * HDD + s * 32 + lg * 8];
  }
  float cq0 = ch[iq0], cq1 = ch[iq1];

  float lsum0 = 0.f, lsum1 = 0.f;
  f32x4_t oacc0[4], oacc1[4];
#pragma unroll
  for (int fn = 0; fn < 4; fn++) {
    oacc0[fn] = (f32x4_t){0.f, 0.f, 0.f, 0.f};
    oacc1[fn] = (f32x4_t){0.f, 0.f, 0.f, 0.f};
  }

  const float SCL = 0.125f * LOG2E;

  // prologue: stage kv tile 0 into buffer 0
  async_copy16(gk0, &Kls[0][s0 * 8]);
  async_copy16(gk1, &Kls[0][s1 * 8]);
  async_copy16(gv0, &Vls[0][s0 * 8]);
  async_copy16(gv1, &Vls[0][s1 * 8]);
  __syncthreads();

  int cur = 0;
  for (int kvt = 0; kvt < ntiles; kvt++) {
    // stage next tile into the other buffer BEFORE computing this one
    if (kvt + 1 < ntiles) {
      size_t kvn = (size_t)(kvt + 1) * KVBLK;
      async_copy16(gk0 + kvn * HDD, &Kls[cur ^ 1][s0 * 8]);
      async_copy16(gk1 + kvn * HDD, &Kls[cur ^ 1][s1 * 8]);
      async_copy16(gv0 + kvn, &Vls[cur ^ 1][s0 * 8]);
      async_copy16(gv1 + kvn, &Vls[cur ^ 1][s1 * 8]);
    }
    if (kvt <= tdiag) {  // wave-uniform: beyond the diagonal this wave has no work
      int kv0 = kvt * KVBLK;
      const u16* Kb = Kls[cur];
      const u16* Vb = Vls[cur];
      float4 ckv[4];
#pragma unroll
      for (int f = 0; f < 4; f++)
        ckv[f] = *(const float4*)&ch[kv0 + f * 16 + lg * 4];

      // S^T = K . Q^T for both q-groups: each K fragment feeds 2 MFMA
      f32x4_t sa0[4], sa1[4];
#pragma unroll
      for (int f = 0; f < 4; f++) {
        sa0[f] = (f32x4_t){0.f, 0.f, 0.f, 0.f};
        sa1[f] = (f32x4_t){0.f, 0.f, 0.f, 0.f};
      }
      __builtin_amdgcn_s_setprio(1);
#pragma unroll
      for (int f = 0; f < 4; f++) {
        int row = f * 16 + lr;
#pragma unroll
        for (int s = 0; s < 2; s++) {
          int boff = (row * 128 + s * 64 + lg * 16) ^ ((row & 7) << 4);
          bf16x8_t kf = *(const bf16x8_t*)((const char*)Kb + boff);
          sa0[f] = __builtin_amdgcn_mfma_f32_16x16x32_bf16(kf, qf0[s], sa0[f], 0, 0, 0);
          sa1[f] = __builtin_amdgcn_mfma_f32_16x16x32_bf16(kf, qf1[s], sa1[f], 0, 0, 0);
        }
      }
      __builtin_amdgcn_s_setprio(0);

      // fixed-max softmax in exp2 domain, two independent chains
      bool diag = (kvt == tdiag);
      float pv0[4][4], pv1[4][4];
#pragma unroll
      for (int f = 0; f < 4; f++) {
        const float* ckp = &ckv[f].x;
#pragma unroll
        for (int r = 0; r < 4; r++) {
          int jj = kv0 + f * 16 + lg * 4 + r;
          float e0 = exp2f(fmaf(sa0[f][r], SCL, cq0 - ckp[r]));
          float e1 = exp2f(fmaf(sa1[f][r], SCL, cq1 - ckp[r]));
          if (diag && jj > iq0) e0 = 0.f;
          if (diag && jj > iq1) e1 = 0.f;
          pv0[f][r] = e0; lsum0 += e0;
          pv1[f][r] = e1; lsum1 += e1;
        }
      }

      // pack P to bf16 pairs + permlane network -> B-fragments in regs (per group)
      bf16x8_t pa0[2], pa1[2];
#pragma unroll
      for (int s = 0; s < 2; s++) {
        {
          uint32_t x0 = packbf2(pv0[2 * s][0], pv0[2 * s][1]);
          uint32_t x1 = packbf2(pv0[2 * s][2], pv0[2 * s][3]);
          uint32_t y0 = packbf2(pv0[2 * s + 1][0], pv0[2 * s + 1][1]);
          uint32_t y1 = packbf2(pv0[2 * s + 1][2], pv0[2 * s + 1][3]);
          asm volatile("v_permlane32_swap_b32 %0, %1" : "+v"(x0), "+v"(y0));
          asm volatile("v_permlane32_swap_b32 %0, %1" : "+v"(x1), "+v"(y1));
          asm volatile("v_permlane16_swap_b32 %0, %1" : "+v"(x0), "+v"(y0));
          asm volatile("v_permlane16_swap_b32 %0, %1" : "+v"(x1), "+v"(y1));
          union { uint32_t u[4]; bf16x8_t v; } pk;
          pk.u[0] = x0; pk.u[1] = x1; pk.u[2] = y0; pk.u[3] = y1;
          pa0[s] = pk.v;
        }
        {
          uint32_t x0 = packbf2(pv1[2 * s][0], pv1[2 * s][1]);
          uint32_t x1 = packbf2(pv1[2 * s][2], pv1[2 * s][3]);
          uint32_t y0 = packbf2(pv1[2 * s + 1][0], pv1[2 * s + 1][1]);
          uint32_t y1 = packbf2(pv1[2 * s + 1][2], pv1[2 * s + 1][3]);
          asm volatile("v_permlane32_swap_b32 %0, %1" : "+v"(x0), "+v"(y0));
          asm volatile("v_permlane32_swap_b32 %0, %1" : "+v"(x1), "+v"(y1));
          asm volatile("v_permlane16_swap_b32 %0, %1" : "+v"(x0), "+v"(y0));
          asm volatile("v_permlane16_swap_b32 %0, %1" : "+v"(x1), "+v"(y1));
          union { uint32_t u[4]; bf16x8_t v; } pk;
          pk.u[0] = x0; pk.u[1] = x1; pk.u[2] = y0; pk.u[3] = y1;
          pa1[s] = pk.v;
        }
      }

      // O^T += V^T . P for both groups: each V fragment feeds 2 MFMA
      __builtin_amdgcn_s_setprio(1);
#pragma unroll
      for (int fn = 0; fn < 4; fn++) {
        int row = fn * 16 + lr;
#pragma unroll
        for (int s = 0; s < 2; s++) {
          int boff = (row * 128 + s * 64 + lg * 16) ^ ((row & 7) << 4);
          bf16x8_t vf = *(const bf16x8_t*)((const char*)Vb + boff);
          oacc0[fn] = __builtin_amdgcn_mfma_f32_16x16x32_bf16(vf, pa0[s], oacc0[fn], 0, 0, 0);
          oacc1[fn] = __builtin_amdgcn_mfma_f32_16x16x32_bf16(vf, pa1[s], oacc1[fn], 0, 0, 0);
        }
      }
      __builtin_amdgcn_s_setprio(0);
    }
    __syncthreads();
    cur ^= 1;
  }

  // l-reduce over the 4 lanes sharing lr
  lsum0 += __shfl_xor(lsum0, 16, 64);
  lsum0 += __shfl_xor(lsum0, 32, 64);
  lsum1 += __shfl_xor(lsum1, 16, 64);
  lsum1 += __shfl_xor(lsum1, 32, 64);
  float rinv0 = 1.0f / lsum0, rinv1 = 1.0f / lsum1;

  // output: two q-rows per lane, packed 8B stores
  u16* orow0 = O + ((size_t)(b * NN + iq0)) * DD + h * HDD;
  u16* orow1 = O + ((size_t)(b * NN + iq1)) * DD + h * HDD;
#pragma unroll
  for (int fn = 0; fn < 4; fn++) {
    ushort4 o4;
    o4.x = f2bf(oacc0[fn][0] * rinv0);
    o4.y = f2bf(oacc0[fn][1] * rinv0);
    o4.z = f2bf(oacc0[fn][2] * rinv0);
    o4.w = f2bf(oacc0[fn][3] * rinv0);
    *(ushort4*)&orow0[fn * 16 + lg * 4] = o4;
    ushort4 o5;
    o5.x = f2bf(oacc1[fn][0] * rinv1);
    o5.y = f2bf(oacc1[fn][1] * rinv1);
    o5.z = f2bf(oacc1[fn][2] * rinv1);
    o5.w = f2bf(oacc1[fn][3] * rinv1);
    *(ushort4*)&orow1[fn * 16 + lg * 4] = o5;
  }
}

extern "C" void kernel_launch(void* const* d_in, const int* in_sizes, int n_in,
                              void* d_out, int out_size, void* d_ws, size_t ws_size,
                              hipStream_t stream) {
  const float* x  = (const float*)d_in[0];
  const float* Wq = (const float*)d_in[1];
  const float* Wk = (const float*)d_in[2];
  const float* Wv = (const float*)d_in[3];
  const float* Wo = (const float*)d_in[4];
  const float* Wf = (const float*)d_in[5];
  float* out = (float*)d_out;
  char* ws = (char*)d_ws;
  const size_t MB = 1024 * 1024;
  u16* x_bf  = (u16*)(ws + 0);        // 8 MB
  u16* WqkvT = (u16*)(ws + 8 * MB);   // 6 MB: WqT | WkT | WvT contiguous [3072][1024]
  u16* WoT   = (u16*)(ws + 14 * MB);  // 2 MB
  u16* Qw    = (u16*)(ws + 16 * MB);  // 8 MB [bh][n][hd]
  u16* Kw    = (u16*)(ws + 24 * MB);  // 8 MB
  u16* Vw    = (u16*)(ws + 32 * MB);  // 8 MB [bh][hd][n]
  u16* Ow    = (u16*)(ws + 40 * MB);  // 8 MB [b n d]
  float* lf  = (float*)(ws + 48 * MB);            // 256 KB
  float* cwp = (float*)(ws + 48 * MB + 262144);   // 256 KB (pre-scaled by log2e)
  u16* Vtmp  = (u16*)(ws + 49 * MB);  // 8 MB [bh][n][hd]

  transpose_w_kernel<<<dim3(256, 4), 256, 0, stream>>>(Wq, Wk, Wv, Wo, WqkvT);
  logf_kernel<<<4096, 256, 0, stream>>>(x, Wf, lf, x_bf);
  cumsum_kernel<<<32, 64, 0, stream>>>(lf, cwp);
  // fused QKV GEMM: N = 3072
  gemm_kernel<<<dim3(24, 32), 512, 0, stream>>>(x_bf, WqkvT, Qw, Kw, Vtmp, nullptr, 0);
  transpose_v_kernel<<<dim3(32, 32), 256, 0, stream>>>(Vtmp, Vw);
  attn_kernel<<<512, 256, 0, stream>>>(Qw, Kw, Vw, cwp, Ow);
  gemm_kernel<<<dim3(8, 32), 512, 0, stream>>>(Ow, WqkvT + (size_t)3 * DD * DD, nullptr, nullptr, nullptr, out, 1);
}

// Round 12
// 137.600 us; speedup vs baseline: 1.1207x; 1.1207x over previous
//
#include <hip/hip_runtime.h>
#include <hip/hip_bf16.h>
#include <stdint.h>

#define NN 2048
#define DD 1024
#define HH 16
#define HDD 64
#define KVBLK 64

typedef unsigned short u16;
typedef __attribute__((ext_vector_type(8))) __bf16 bf16x8_t;
typedef __attribute__((ext_vector_type(4))) float f32x4_t;

#define LOG2E 1.44269504f

static __device__ __forceinline__ u16 f2bf(float f) {
  union { float f; uint32_t u; } v; v.f = f;
  uint32_t r = v.u + 0x7FFFu + ((v.u >> 16) & 1u);
  return (u16)(r >> 16);
}

static __device__ __forceinline__ uint32_t packbf2(float a, float b) {
  __hip_bfloat162 h2 = __float22bfloat162_rn(make_float2(a, b));
  union { __hip_bfloat162 hh; uint32_t u; } cvt; cvt.hh = h2;
  return cvt.u;
}

// P[4][4] (quarters of one q-row) -> two MFMA B-fragments via permlane network
static __device__ __forceinline__ void make_pa(const float pv[4][4], bf16x8_t pa[2]) {
#pragma unroll
  for (int s = 0; s < 2; s++) {
    uint32_t x0 = packbf2(pv[2 * s][0], pv[2 * s][1]);
    uint32_t x1 = packbf2(pv[2 * s][2], pv[2 * s][3]);
    uint32_t y0 = packbf2(pv[2 * s + 1][0], pv[2 * s + 1][1]);
    uint32_t y1 = packbf2(pv[2 * s + 1][2], pv[2 * s + 1][3]);
    asm volatile("v_permlane32_swap_b32 %0, %1" : "+v"(x0), "+v"(y0));
    asm volatile("v_permlane32_swap_b32 %0, %1" : "+v"(x1), "+v"(y1));
    asm volatile("v_permlane16_swap_b32 %0, %1" : "+v"(x0), "+v"(y0));
    asm volatile("v_permlane16_swap_b32 %0, %1" : "+v"(x1), "+v"(y1));
    union { uint32_t u[4]; bf16x8_t v; } pk;
    pk.u[0] = x0; pk.u[1] = x1; pk.u[2] = y0; pk.u[3] = y1;
    pa[s] = pk.v;
  }
}

// async global->LDS, 16B per lane. LDS dest must be wave-uniform base + lane*16.
static __device__ __forceinline__ void async_copy16(const void* g, void* l) {
  __builtin_amdgcn_global_load_lds((const __attribute__((address_space(1))) void*)g,
                                   (__attribute__((address_space(3))) void*)l, 16, 0, 0);
}

// ---------------- weight transpose+cast: Wt[n][k] = W[k][n], 4 weights in one launch ----------------
__global__ void transpose_w_kernel(const float* __restrict__ W0, const float* __restrict__ W1,
                                   const float* __restrict__ W2, const float* __restrict__ W3,
                                   u16* __restrict__ Wt) {
  __shared__ float tile[64][65];
  const float* W = blockIdx.y == 0 ? W0 : blockIdx.y == 1 ? W1 : blockIdx.y == 2 ? W2 : W3;
  u16* out = Wt + (size_t)blockIdx.y * DD * DD;
  int bx = blockIdx.x & 15;   // n tile
  int by = blockIdx.x >> 4;   // k tile
  int t = threadIdx.x;
  int c = t & 63, r4 = t >> 6;
#pragma unroll
  for (int i = 0; i < 16; i++) {
    int row = i * 4 + r4;
    tile[row][c] = W[(by * 64 + row) * DD + bx * 64 + c];
  }
  __syncthreads();
#pragma unroll
  for (int i = 0; i < 16; i++) {
    int row = i * 4 + r4;
    out[(bx * 64 + row) * DD + by * 64 + c] = f2bf(tile[c][row]);
  }
}

// ---------------- log-sigmoid gate + fused x->bf16 cast ----------------
__global__ void logf_kernel(const float* __restrict__ x, const float* __restrict__ Wf,
                            float* __restrict__ lf, u16* __restrict__ xb) {
  __shared__ float xs[DD];
  __shared__ float part[16][17];
  int row = blockIdx.x;   // b*N + n
  int t = threadIdx.x;    // 256
  float4 v = *(const float4*)&x[(size_t)row * DD + t * 4];
  *(float4*)&xs[t * 4] = v;
  ushort4 o;
  o.x = f2bf(v.x); o.y = f2bf(v.y); o.z = f2bf(v.z); o.w = f2bf(v.w);
  *(ushort4*)&xb[(size_t)row * DD + t * 4] = o;
  __syncthreads();
  int h = t & 15, chunk = t >> 4;
  float s = 0.f;
#pragma unroll 8
  for (int e = 0; e < 64; e++)
    s += xs[chunk * 64 + e] * Wf[(chunk * 64 + e) * HH + h];
  part[chunk][h] = s;
  __syncthreads();
  if (t < 16) {
    float z = 0.f;
#pragma unroll
    for (int i = 0; i < 16; i++) z += part[i][t];
    float ls = fminf(z, 0.f) - log1pf(__expf(-fabsf(z)));
    int b = row >> 11, n = row & (NN - 1);
    lf[(b * HH + t) * NN + n] = ls;
  }
}

// ---------------- cumsum over n per (b,h): float4/lane; output pre-scaled by log2(e) ----------------
__global__ void cumsum_kernel(const float* __restrict__ lf, float* __restrict__ c) {
  int bh = blockIdx.x;
  int lane = threadIdx.x;  // 64
  const float* in = lf + bh * NN;
  float* out = c + bh * NN;
  float carry = 0.f;
  for (int t0 = 0; t0 < NN; t0 += 256) {
    float4 v = *(const float4*)&in[t0 + lane * 4];
    float s1 = v.x + v.y, s2 = s1 + v.z, s3 = s2 + v.w;
    float incl = s3;
#pragma unroll
    for (int off = 1; off < 64; off <<= 1) {
      float u = __shfl_up(incl, off, 64);
      if (lane >= off) incl += u;
    }
    float excl = incl - s3 + carry;
    float4 o;
    o.x = (excl + v.x) * LOG2E; o.y = (excl + s1) * LOG2E;
    o.z = (excl + s2) * LOG2E; o.w = (excl + s3) * LOG2E;
    *(float4*)&out[t0 + lane * 4] = o;
    carry = __shfl(incl, 63, 64) + carry;
  }
}

// ---------------- GEMM 128x128 tile, BK=64, swizzled LDS, 512 threads (8 waves, 2x4) ----------------
// mode 0 (QKV fused): Wt is [3072][1024]; Q/K -> [bh][n][hd] bf16; V -> [bh][hd][n] bf16 (fused transpose)
// mode 1 (output):    Wt is [1024][1024]; fp32 flat to oF
__global__ __launch_bounds__(512, 4) void gemm_kernel(const u16* __restrict__ A,
                                                      const u16* __restrict__ Wt,
                                                      u16* __restrict__ oQ, u16* __restrict__ oK,
                                                      u16* __restrict__ oV, float* __restrict__ oF,
                                                      int mode) {
  __shared__ u16 Als[128 * 64];
  __shared__ u16 Bls[128 * 64];
  int m0 = blockIdx.y * 128, n0 = blockIdx.x * 128;
  int tid = threadIdx.x;
  int lane = tid & 63, w = tid >> 6;   // 8 waves
  int wm = w >> 2, wn = w & 3;         // 2 x 4 wave grid: 64 rows x 32 cols each
  int lr = lane & 15, lg = lane >> 4;

  const u16* gA[2]; const u16* gB[2]; u16* lA[2]; u16* lB[2];
#pragma unroll
  for (int j = 0; j < 2; j++) {
    int s = tid + j * 512;
    int row = s >> 3, ch = s & 7;
    int scol = (ch ^ (row & 7)) * 8;
    gA[j] = &A [(size_t)(m0 + row) * DD + scol];
    gB[j] = &Wt[(size_t)(n0 + row) * DD + scol];
    lA[j] = &Als[s * 8];
    lB[j] = &Bls[s * 8];
  }

  f32x4_t acc[4][2];
#pragma unroll
  for (int i = 0; i < 4; i++)
#pragma unroll
    for (int j = 0; j < 2; j++) acc[i][j] = (f32x4_t){0.f, 0.f, 0.f, 0.f};

  for (int kt = 0; kt < DD; kt += 64) {
    __syncthreads();
#pragma unroll
    for (int j = 0; j < 2; j++) {
      async_copy16(gA[j] + kt, lA[j]);
      async_copy16(gB[j] + kt, lB[j]);
    }
    __syncthreads();
#pragma unroll
    for (int kk = 0; kk < 2; kk++) {
      bf16x8_t af[4], bfv[2];
#pragma unroll
      for (int mi = 0; mi < 4; mi++) {
        int row = wm * 64 + mi * 16 + lr;
        int boff = (row * 128 + kk * 64 + lg * 16) ^ ((row & 7) << 4);
        af[mi] = *(const bf16x8_t*)((const char*)Als + boff);
      }
#pragma unroll
      for (int ni = 0; ni < 2; ni++) {
        int row = wn * 32 + ni * 16 + lr;
        int boff = (row * 128 + kk * 64 + lg * 16) ^ ((row & 7) << 4);
        bfv[ni] = *(const bf16x8_t*)((const char*)Bls + boff);
      }
#pragma unroll
      for (int mi = 0; mi < 4; mi++)
#pragma unroll
        for (int ni = 0; ni < 2; ni++)
          acc[mi][ni] = __builtin_amdgcn_mfma_f32_16x16x32_bf16(af[mi], bfv[ni], acc[mi][ni], 0, 0, 0);
    }
  }

  if (mode == 1) {
#pragma unroll
    for (int mi = 0; mi < 4; mi++)
#pragma unroll
      for (int ni = 0; ni < 2; ni++) {
        int gcol = n0 + wn * 32 + ni * 16 + lr;
#pragma unroll
        for (int r = 0; r < 4; r++) {
          int grow = m0 + wm * 64 + mi * 16 + lg * 4 + r;
          oF[(size_t)grow * DD + gcol] = acc[mi][ni][r];
        }
      }
  } else {
    int which = n0 >> 10;
    int nl0 = n0 & 1023;
    if (which == 2) {
      // V: write transposed [bh][hd][n] -- 4 consecutive n per thread = packed 8B store
#pragma unroll
      for (int mi = 0; mi < 4; mi++)
#pragma unroll
        for (int ni = 0; ni < 2; ni++) {
          int gcol = nl0 + wn * 32 + ni * 16 + lr;
          int h = gcol >> 6, hd = gcol & 63;
          int grow0 = m0 + wm * 64 + mi * 16 + lg * 4;
          int b = grow0 >> 11, n = grow0 & (NN - 1);
          ushort4 o4;
          o4.x = f2bf(acc[mi][ni][0]);
          o4.y = f2bf(acc[mi][ni][1]);
          o4.z = f2bf(acc[mi][ni][2]);
          o4.w = f2bf(acc[mi][ni][3]);
          *(ushort4*)&oV[((size_t)(b * HH + h) * HDD + hd) * NN + n] = o4;
        }
    } else {
      u16* outp = which == 0 ? oQ : oK;
#pragma unroll
      for (int mi = 0; mi < 4; mi++)
#pragma unroll
        for (int ni = 0; ni < 2; ni++) {
          int gcol = nl0 + wn * 32 + ni * 16 + lr;
          int h = gcol >> 6, hd = gcol & 63;
#pragma unroll
          for (int r = 0; r < 4; r++) {
            int grow = m0 + wm * 64 + mi * 16 + lg * 4 + r;
            int b = grow >> 11, n = grow & (NN - 1);
            outp[((size_t)(b * HH + h) * NN + n) * HDD + hd] = f2bf(acc[mi][ni][r]);
          }
        }
    }
  }
}

// ---------------- flash attention: concurrent (heavy,light) pair, shared K/V staging ----------------
// Block owns tiles th=31-p (heavy) and tl=p (light), each 64 q-rows, 16 rows/wave/tile.
// KV loop covers heavy's range (32-p iters, max 32). Iters 0..tl are DUAL: each K/V
// fragment read feeds both tiles' MFMAs (2x FLOP per LDS byte) + two independent softmax
// chains (ILP). Iters tl+1..th are the round-8 single body. Per-block work = 33 units
// everywhere (uniform makespan); staging/barriers = 32-p (avg 24.5 vs 33). Heavy never
// masked in dual phase (th>=16>tl). Fixed-max softmax in exp2 domain; swapped QK^T;
// permlane P-in-reg; XCD-swizzled grid (round-7).
__global__ __launch_bounds__(256) void attn_kernel(const u16* __restrict__ Q,
                                                   const u16* __restrict__ K,
                                                   const u16* __restrict__ Vt,
                                                   const float* __restrict__ cw,
                                                   u16* __restrict__ O) {
  __shared__ u16 Kls[2][KVBLK * 64];
  __shared__ u16 Vls[2][64 * KVBLK];
  int flat = blockIdx.y * gridDim.x + blockIdx.x;  // grid (16, 32) = 512
  int swz = (flat & 7) * 64 + (flat >> 3);         // bijective, bh-contiguous per XCD
  int pidx = swz & 15, bh = swz >> 4;
  int tid = threadIdx.x;
  int lane = tid & 63, w = tid >> 6;
  int lr = lane & 15, lg = lane >> 4;
  const u16* Qh = Q + (size_t)bh * NN * HDD;
  const u16* Kh = K + (size_t)bh * NN * HDD;
  const u16* Vh = Vt + (size_t)bh * HDD * NN;
  const float* ch = cw + bh * NN;   // pre-scaled by log2e
  int b = bh >> 4, h = bh & 15;

  int th = 31 - pidx, tl = pidx;
  int qbH = th * 64 + w * 16, qbL = tl * 64 + w * 16;
  int iqH = qbH + lr, iqL = qbL + lr;
  int ntiles = th + 1;

  // staging: 512 slots of 16B per 8KB tile; LDS linear at slot*16B;
  // swizzle folded into SOURCE chunk: chunk ^ (row&7).
  int s0 = tid, s1 = tid + 256;
  int r0 = s0 >> 3, p0 = s0 & 7;
  int r1 = s1 >> 3, p1 = s1 & 7;
  const u16* gk0 = &Kh[(size_t)r0 * HDD + ((p0 ^ (r0 & 7)) * 8)];
  const u16* gk1 = &Kh[(size_t)r1 * HDD + ((p1 ^ (r1 & 7)) * 8)];
  const u16* gv0 = &Vh[(size_t)r0 * NN + ((p0 ^ (r0 & 7)) * 8)];
  const u16* gv1 = &Vh[(size_t)r1 * NN + ((p1 ^ (r1 & 7)) * 8)];

  bf16x8_t qfH[2], qfL[2];
#pragma unroll
  for (int s = 0; s < 2; s++) {
    qfH[s] = *(const bf16x8_t*)&Qh[(size_t)iqH * HDD + s * 32 + lg * 8];
    qfL[s] = *(const bf16x8_t*)&Qh[(size_t)iqL * HDD + s * 32 + lg * 8];
  }
  float cqH = ch[iqH], cqL = ch[iqL];

  float lsumH = 0.f, lsumL = 0.f;
  f32x4_t oaccH[4], oaccL[4];
#pragma unroll
  for (int fn = 0; fn < 4; fn++) {
    oaccH[fn] = (f32x4_t){0.f, 0.f, 0.f, 0.f};
    oaccL[fn] = (f32x4_t){0.f, 0.f, 0.f, 0.f};
  }

  const float SCL = 0.125f * LOG2E;

  // prologue: stage kv tile 0 into buffer 0
  async_copy16(gk0, &Kls[0][s0 * 8]);
  async_copy16(gk1, &Kls[0][s1 * 8]);
  async_copy16(gv0, &Vls[0][s0 * 8]);
  async_copy16(gv1, &Vls[0][s1 * 8]);
  __syncthreads();

  int cur = 0;
  int kvt = 0;

  // ---- DUAL phase: kvt 0..tl (heavy never at diagonal here: th >= 16 > tl) ----
  for (; kvt <= tl; kvt++) {
    if (kvt + 1 < ntiles) {
      size_t kvn = (size_t)(kvt + 1) * KVBLK;
      async_copy16(gk0 + kvn * HDD, &Kls[cur ^ 1][s0 * 8]);
      async_copy16(gk1 + kvn * HDD, &Kls[cur ^ 1][s1 * 8]);
      async_copy16(gv0 + kvn, &Vls[cur ^ 1][s0 * 8]);
      async_copy16(gv1 + kvn, &Vls[cur ^ 1][s1 * 8]);
    }
    int kv0 = kvt * KVBLK;
    const u16* Kb = Kls[cur];
    const u16* Vb = Vls[cur];
    float4 ckv[4];
#pragma unroll
    for (int f = 0; f < 4; f++)
      ckv[f] = *(const float4*)&ch[kv0 + f * 16 + lg * 4];

    f32x4_t saH[4], saL[4];
#pragma unroll
    for (int f = 0; f < 4; f++) {
      saH[f] = (f32x4_t){0.f, 0.f, 0.f, 0.f};
      saL[f] = (f32x4_t){0.f, 0.f, 0.f, 0.f};
    }
    __builtin_amdgcn_s_setprio(1);
#pragma unroll
    for (int f = 0; f < 4; f++) {
      int row = f * 16 + lr;
#pragma unroll
      for (int s = 0; s < 2; s++) {
        int boff = (row * 128 + s * 64 + lg * 16) ^ ((row & 7) << 4);
        bf16x8_t kf = *(const bf16x8_t*)((const char*)Kb + boff);
        saH[f] = __builtin_amdgcn_mfma_f32_16x16x32_bf16(kf, qfH[s], saH[f], 0, 0, 0);
        saL[f] = __builtin_amdgcn_mfma_f32_16x16x32_bf16(kf, qfL[s], saL[f], 0, 0, 0);
      }
    }
    __builtin_amdgcn_s_setprio(0);

    bool diagL = (kvt == tl);
    float pvH[4][4], pvL[4][4];
#pragma unroll
    for (int f = 0; f < 4; f++) {
      const float* ckp = &ckv[f].x;
#pragma unroll
      for (int r = 0; r < 4; r++) {
        int jj = kv0 + f * 16 + lg * 4 + r;
        float eH = exp2f(fmaf(saH[f][r], SCL, cqH - ckp[r]));
        float eL = exp2f(fmaf(saL[f][r], SCL, cqL - ckp[r]));
        if (diagL && jj > iqL) eL = 0.f;
        pvH[f][r] = eH; lsumH += eH;
        pvL[f][r] = eL; lsumL += eL;
      }
    }

    bf16x8_t paH[2], paL[2];
    make_pa(pvH, paH);
    make_pa(pvL, paL);

    __builtin_amdgcn_s_setprio(1);
#pragma unroll
    for (int fn = 0; fn < 4; fn++) {
      int row = fn * 16 + lr;
#pragma unroll
      for (int s = 0; s < 2; s++) {
        int boff = (row * 128 + s * 64 + lg * 16) ^ ((row & 7) << 4);
        bf16x8_t vf = *(const bf16x8_t*)((const char*)Vb + boff);
        oaccH[fn] = __builtin_amdgcn_mfma_f32_16x16x32_bf16(vf, paH[s], oaccH[fn], 0, 0, 0);
        oaccL[fn] = __builtin_amdgcn_mfma_f32_16x16x32_bf16(vf, paL[s], oaccL[fn], 0, 0, 0);
      }
    }
    __builtin_amdgcn_s_setprio(0);
    __syncthreads();
    cur ^= 1;
  }

  // ---- SINGLE phase: kvt tl+1..th (heavy only; diag at kvt == th) ----
  for (; kvt < ntiles; kvt++) {
    if (kvt + 1 < ntiles) {
      size_t kvn = (size_t)(kvt + 1) * KVBLK;
      async_copy16(gk0 + kvn * HDD, &Kls[cur ^ 1][s0 * 8]);
      async_copy16(gk1 + kvn * HDD, &Kls[cur ^ 1][s1 * 8]);
      async_copy16(gv0 + kvn, &Vls[cur ^ 1][s0 * 8]);
      async_copy16(gv1 + kvn, &Vls[cur ^ 1][s1 * 8]);
    }
    int kv0 = kvt * KVBLK;
    const u16* Kb = Kls[cur];
    const u16* Vb = Vls[cur];
    float4 ckv[4];
#pragma unroll
    for (int f = 0; f < 4; f++)
      ckv[f] = *(const float4*)&ch[kv0 + f * 16 + lg * 4];

    f32x4_t saH[4];
#pragma unroll
    for (int f = 0; f < 4; f++) saH[f] = (f32x4_t){0.f, 0.f, 0.f, 0.f};
    __builtin_amdgcn_s_setprio(1);
#pragma unroll
    for (int f = 0; f < 4; f++) {
      int row = f * 16 + lr;
#pragma unroll
      for (int s = 0; s < 2; s++) {
        int boff = (row * 128 + s * 64 + lg * 16) ^ ((row & 7) << 4);
        bf16x8_t kf = *(const bf16x8_t*)((const char*)Kb + boff);
        saH[f] = __builtin_amdgcn_mfma_f32_16x16x32_bf16(kf, qfH[s], saH[f], 0, 0, 0);
      }
    }
    __builtin_amdgcn_s_setprio(0);

    bool diag = (kvt == th);
    float pvH[4][4];
#pragma unroll
    for (int f = 0; f < 4; f++) {
      const float* ckp = &ckv[f].x;
#pragma unroll
      for (int r = 0; r < 4; r++) {
        int jj = kv0 + f * 16 + lg * 4 + r;
        float eH = exp2f(fmaf(saH[f][r], SCL, cqH - ckp[r]));
        if (diag && jj > iqH) eH = 0.f;
        pvH[f][r] = eH; lsumH += eH;
      }
    }

    bf16x8_t paH[2];
    make_pa(pvH, paH);

    __builtin_amdgcn_s_setprio(1);
#pragma unroll
    for (int fn = 0; fn < 4; fn++) {
      int row = fn * 16 + lr;
#pragma unroll
      for (int s = 0; s < 2; s++) {
        int boff = (row * 128 + s * 64 + lg * 16) ^ ((row & 7) << 4);
        bf16x8_t vf = *(const bf16x8_t*)((const char*)Vb + boff);
        oaccH[fn] = __builtin_amdgcn_mfma_f32_16x16x32_bf16(vf, paH[s], oaccH[fn], 0, 0, 0);
      }
    }
    __builtin_amdgcn_s_setprio(0);
    __syncthreads();
    cur ^= 1;
  }

  // l-reduce over the 4 lanes sharing lr
  lsumH += __shfl_xor(lsumH, 16, 64);
  lsumH += __shfl_xor(lsumH, 32, 64);
  lsumL += __shfl_xor(lsumL, 16, 64);
  lsumL += __shfl_xor(lsumL, 32, 64);
  float rinvH = 1.0f / lsumH, rinvL = 1.0f / lsumL;

  // outputs: both tiles, packed 8B stores
  u16* orowH = O + ((size_t)(b * NN + iqH)) * DD + h * HDD;
  u16* orowL = O + ((size_t)(b * NN + iqL)) * DD + h * HDD;
#pragma unroll
  for (int fn = 0; fn < 4; fn++) {
    ushort4 o4;
    o4.x = f2bf(oaccH[fn][0] * rinvH);
    o4.y = f2bf(oaccH[fn][1] * rinvH);
    o4.z = f2bf(oaccH[fn][2] * rinvH);
    o4.w = f2bf(oaccH[fn][3] * rinvH);
    *(ushort4*)&orowH[fn * 16 + lg * 4] = o4;
    ushort4 o5;
    o5.x = f2bf(oaccL[fn][0] * rinvL);
    o5.y = f2bf(oaccL[fn][1] * rinvL);
    o5.z = f2bf(oaccL[fn][2] * rinvL);
    o5.w = f2bf(oaccL[fn][3] * rinvL);
    *(ushort4*)&orowL[fn * 16 + lg * 4] = o5;
  }
}

extern "C" void kernel_launch(void* const* d_in, const int* in_sizes, int n_in,
                              void* d_out, int out_size, void* d_ws, size_t ws_size,
                              hipStream_t stream) {
  const float* x  = (const float*)d_in[0];
  const float* Wq = (const float*)d_in[1];
  const float* Wk = (const float*)d_in[2];
  const float* Wv = (const float*)d_in[3];
  const float* Wo = (const float*)d_in[4];
  const float* Wf = (const float*)d_in[5];
  float* out = (float*)d_out;
  char* ws = (char*)d_ws;
  const size_t MB = 1024 * 1024;
  u16* x_bf  = (u16*)(ws + 0);        // 8 MB
  u16* WqkvT = (u16*)(ws + 8 * MB);   // 6 MB: WqT | WkT | WvT contiguous [3072][1024]
  u16* WoT   = (u16*)(ws + 14 * MB);  // 2 MB
  u16* Qw    = (u16*)(ws + 16 * MB);  // 8 MB [bh][n][hd]
  u16* Kw    = (u16*)(ws + 24 * MB);  // 8 MB
  u16* Vw    = (u16*)(ws + 32 * MB);  // 8 MB [bh][hd][n] (written transposed by gemm)
  u16* Ow    = (u16*)(ws + 40 * MB);  // 8 MB [b n d]
  float* lf  = (float*)(ws + 48 * MB);            // 256 KB
  float* cwp = (float*)(ws + 48 * MB + 262144);   // 256 KB (pre-scaled by log2e)

  transpose_w_kernel<<<dim3(256, 4), 256, 0, stream>>>(Wq, Wk, Wv, Wo, WqkvT);
  logf_kernel<<<4096, 256, 0, stream>>>(x, Wf, lf, x_bf);
  cumsum_kernel<<<32, 64, 0, stream>>>(lf, cwp);
  // fused QKV GEMM: N = 3072; V written directly transposed
  gemm_kernel<<<dim3(24, 32), 512, 0, stream>>>(x_bf, WqkvT, Qw, Kw, Vw, nullptr, 0);
  attn_kernel<<<dim3(16, 32), 256, 0, stream>>>(Qw, Kw, Vw, cwp, Ow);
  gemm_kernel<<<dim3(8, 32), 512, 0, stream>>>(Ow, WqkvT + (size_t)3 * DD * DD, nullptr, nullptr, nullptr, out, 1);
}

// Round 13
// 132.643 us; speedup vs baseline: 1.1626x; 1.0374x over previous
//
#include <hip/hip_runtime.h>
#include <hip/hip_bf16.h>
#include <stdint.h>

#define NN 2048
#define DD 1024
#define HH 16
#define HDD 64
#define QBLK 64
#define KVBLK 64

typedef unsigned short u16;
typedef __attribute__((ext_vector_type(8))) __bf16 bf16x8_t;
typedef __attribute__((ext_vector_type(4))) float f32x4_t;

#define LOG2E 1.44269504f

static __device__ __forceinline__ u16 f2bf(float f) {
  union { float f; uint32_t u; } v; v.f = f;
  uint32_t r = v.u + 0x7FFFu + ((v.u >> 16) & 1u);
  return (u16)(r >> 16);
}

static __device__ __forceinline__ uint32_t packbf2(float a, float b) {
  __hip_bfloat162 h2 = __float22bfloat162_rn(make_float2(a, b));
  union { __hip_bfloat162 hh; uint32_t u; } cvt; cvt.hh = h2;
  return cvt.u;
}

// P[4][4] (quarters of one q-row) -> two MFMA B-fragments via permlane network
static __device__ __forceinline__ void make_pa(const float pv[4][4], bf16x8_t pa[2]) {
#pragma unroll
  for (int s = 0; s < 2; s++) {
    uint32_t x0 = packbf2(pv[2 * s][0], pv[2 * s][1]);
    uint32_t x1 = packbf2(pv[2 * s][2], pv[2 * s][3]);
    uint32_t y0 = packbf2(pv[2 * s + 1][0], pv[2 * s + 1][1]);
    uint32_t y1 = packbf2(pv[2 * s + 1][2], pv[2 * s + 1][3]);
    asm volatile("v_permlane32_swap_b32 %0, %1" : "+v"(x0), "+v"(y0));
    asm volatile("v_permlane32_swap_b32 %0, %1" : "+v"(x1), "+v"(y1));
    asm volatile("v_permlane16_swap_b32 %0, %1" : "+v"(x0), "+v"(y0));
    asm volatile("v_permlane16_swap_b32 %0, %1" : "+v"(x1), "+v"(y1));
    union { uint32_t u[4]; bf16x8_t v; } pk;
    pk.u[0] = x0; pk.u[1] = x1; pk.u[2] = y0; pk.u[3] = y1;
    pa[s] = pk.v;
  }
}

// async global->LDS, 16B per lane. LDS dest must be wave-uniform base + lane*16.
static __device__ __forceinline__ void async_copy16(const void* g, void* l) {
  __builtin_amdgcn_global_load_lds((const __attribute__((address_space(1))) void*)g,
                                   (__attribute__((address_space(3))) void*)l, 16, 0, 0);
}

// ---------------- weight transpose+cast: Wt[n][k] = W[k][n], 4 weights in one launch ----------------
__global__ void transpose_w_kernel(const float* __restrict__ W0, const float* __restrict__ W1,
                                   const float* __restrict__ W2, const float* __restrict__ W3,
                                   u16* __restrict__ Wt) {
  __shared__ float tile[64][65];
  const float* W = blockIdx.y == 0 ? W0 : blockIdx.y == 1 ? W1 : blockIdx.y == 2 ? W2 : W3;
  u16* out = Wt + (size_t)blockIdx.y * DD * DD;
  int bx = blockIdx.x & 15;   // n tile
  int by = blockIdx.x >> 4;   // k tile
  int t = threadIdx.x;
  int c = t & 63, r4 = t >> 6;
#pragma unroll
  for (int i = 0; i < 16; i++) {
    int row = i * 4 + r4;
    tile[row][c] = W[(by * 64 + row) * DD + bx * 64 + c];
  }
  __syncthreads();
#pragma unroll
  for (int i = 0; i < 16; i++) {
    int row = i * 4 + r4;
    out[(bx * 64 + row) * DD + by * 64 + c] = f2bf(tile[c][row]);
  }
}

// ---------------- log-sigmoid gate + fused x->bf16 cast ----------------
__global__ void logf_kernel(const float* __restrict__ x, const float* __restrict__ Wf,
                            float* __restrict__ lf, u16* __restrict__ xb) {
  __shared__ float xs[DD];
  __shared__ float part[16][17];
  int row = blockIdx.x;   // b*N + n
  int t = threadIdx.x;    // 256
  float4 v = *(const float4*)&x[(size_t)row * DD + t * 4];
  *(float4*)&xs[t * 4] = v;
  ushort4 o;
  o.x = f2bf(v.x); o.y = f2bf(v.y); o.z = f2bf(v.z); o.w = f2bf(v.w);
  *(ushort4*)&xb[(size_t)row * DD + t * 4] = o;
  __syncthreads();
  int h = t & 15, chunk = t >> 4;
  float s = 0.f;
#pragma unroll 8
  for (int e = 0; e < 64; e++)
    s += xs[chunk * 64 + e] * Wf[(chunk * 64 + e) * HH + h];
  part[chunk][h] = s;
  __syncthreads();
  if (t < 16) {
    float z = 0.f;
#pragma unroll
    for (int i = 0; i < 16; i++) z += part[i][t];
    float ls = fminf(z, 0.f) - log1pf(__expf(-fabsf(z)));
    int b = row >> 11, n = row & (NN - 1);
    lf[(b * HH + t) * NN + n] = ls;
  }
}

// ---------------- cumsum over n per (b,h): float4/lane; output pre-scaled by log2(e) ----------------
__global__ void cumsum_kernel(const float* __restrict__ lf, float* __restrict__ c) {
  int bh = blockIdx.x;
  int lane = threadIdx.x;  // 64
  const float* in = lf + bh * NN;
  float* out = c + bh * NN;
  float carry = 0.f;
  for (int t0 = 0; t0 < NN; t0 += 256) {
    float4 v = *(const float4*)&in[t0 + lane * 4];
    float s1 = v.x + v.y, s2 = s1 + v.z, s3 = s2 + v.w;
    float incl = s3;
#pragma unroll
    for (int off = 1; off < 64; off <<= 1) {
      float u = __shfl_up(incl, off, 64);
      if (lane >= off) incl += u;
    }
    float excl = incl - s3 + carry;
    float4 o;
    o.x = (excl + v.x) * LOG2E; o.y = (excl + s1) * LOG2E;
    o.z = (excl + s2) * LOG2E; o.w = (excl + s3) * LOG2E;
    *(float4*)&out[t0 + lane * 4] = o;
    carry = __shfl(incl, 63, 64) + carry;
  }
}

// ---------------- GEMM 128x128 tile, BK=64, swizzled LDS, 512 threads (8 waves, 2x4) ----------------
// mode 0 (QKV fused): Wt is [3072][1024]; Q/K -> [bh][n][hd] bf16; V -> [bh][hd][n] bf16 (fused transpose)
// mode 1 (output):    Wt is [1024][1024]; fp32 flat to oF
__global__ __launch_bounds__(512, 4) void gemm_kernel(const u16* __restrict__ A,
                                                      const u16* __restrict__ Wt,
                                                      u16* __restrict__ oQ, u16* __restrict__ oK,
                                                      u16* __restrict__ oV, float* __restrict__ oF,
                                                      int mode) {
  __shared__ u16 Als[128 * 64];
  __shared__ u16 Bls[128 * 64];
  int m0 = blockIdx.y * 128, n0 = blockIdx.x * 128;
  int tid = threadIdx.x;
  int lane = tid & 63, w = tid >> 6;   // 8 waves
  int wm = w >> 2, wn = w & 3;         // 2 x 4 wave grid: 64 rows x 32 cols each
  int lr = lane & 15, lg = lane >> 4;

  const u16* gA[2]; const u16* gB[2]; u16* lA[2]; u16* lB[2];
#pragma unroll
  for (int j = 0; j < 2; j++) {
    int s = tid + j * 512;
    int row = s >> 3, ch = s & 7;
    int scol = (ch ^ (row & 7)) * 8;
    gA[j] = &A [(size_t)(m0 + row) * DD + scol];
    gB[j] = &Wt[(size_t)(n0 + row) * DD + scol];
    lA[j] = &Als[s * 8];
    lB[j] = &Bls[s * 8];
  }

  f32x4_t acc[4][2];
#pragma unroll
  for (int i = 0; i < 4; i++)
#pragma unroll
    for (int j = 0; j < 2; j++) acc[i][j] = (f32x4_t){0.f, 0.f, 0.f, 0.f};

  for (int kt = 0; kt < DD; kt += 64) {
    __syncthreads();
#pragma unroll
    for (int j = 0; j < 2; j++) {
      async_copy16(gA[j] + kt, lA[j]);
      async_copy16(gB[j] + kt, lB[j]);
    }
    __syncthreads();
#pragma unroll
    for (int kk = 0; kk < 2; kk++) {
      bf16x8_t af[4], bfv[2];
#pragma unroll
      for (int mi = 0; mi < 4; mi++) {
        int row = wm * 64 + mi * 16 + lr;
        int boff = (row * 128 + kk * 64 + lg * 16) ^ ((row & 7) << 4);
        af[mi] = *(const bf16x8_t*)((const char*)Als + boff);
      }
#pragma unroll
      for (int ni = 0; ni < 2; ni++) {
        int row = wn * 32 + ni * 16 + lr;
        int boff = (row * 128 + kk * 64 + lg * 16) ^ ((row & 7) << 4);
        bfv[ni] = *(const bf16x8_t*)((const char*)Bls + boff);
      }
#pragma unroll
      for (int mi = 0; mi < 4; mi++)
#pragma unroll
        for (int ni = 0; ni < 2; ni++)
          acc[mi][ni] = __builtin_amdgcn_mfma_f32_16x16x32_bf16(af[mi], bfv[ni], acc[mi][ni], 0, 0, 0);
    }
  }

  if (mode == 1) {
#pragma unroll
    for (int mi = 0; mi < 4; mi++)
#pragma unroll
      for (int ni = 0; ni < 2; ni++) {
        int gcol = n0 + wn * 32 + ni * 16 + lr;
#pragma unroll
        for (int r = 0; r < 4; r++) {
          int grow = m0 + wm * 64 + mi * 16 + lg * 4 + r;
          oF[(size_t)grow * DD + gcol] = acc[mi][ni][r];
        }
      }
  } else {
    int which = n0 >> 10;
    int nl0 = n0 & 1023;
    if (which == 2) {
      // V: write transposed [bh][hd][n] -- 4 consecutive n per thread = packed 8B store
#pragma unroll
      for (int mi = 0; mi < 4; mi++)
#pragma unroll
        for (int ni = 0; ni < 2; ni++) {
          int gcol = nl0 + wn * 32 + ni * 16 + lr;
          int h = gcol >> 6, hd = gcol & 63;
          int grow0 = m0 + wm * 64 + mi * 16 + lg * 4;
          int b = grow0 >> 11, n = grow0 & (NN - 1);
          ushort4 o4;
          o4.x = f2bf(acc[mi][ni][0]);
          o4.y = f2bf(acc[mi][ni][1]);
          o4.z = f2bf(acc[mi][ni][2]);
          o4.w = f2bf(acc[mi][ni][3]);
          *(ushort4*)&oV[((size_t)(b * HH + h) * HDD + hd) * NN + n] = o4;
        }
    } else {
      u16* outp = which == 0 ? oQ : oK;
#pragma unroll
      for (int mi = 0; mi < 4; mi++)
#pragma unroll
        for (int ni = 0; ni < 2; ni++) {
          int gcol = nl0 + wn * 32 + ni * 16 + lr;
          int h = gcol >> 6, hd = gcol & 63;
#pragma unroll
          for (int r = 0; r < 4; r++) {
            int grow = m0 + wm * 64 + mi * 16 + lg * 4 + r;
            int b = grow >> 11, n = grow & (NN - 1);
            outp[((size_t)(b * HH + h) * NN + n) * HDD + hd] = f2bf(acc[mi][ni][r]);
          }
        }
    }
  }
}

// ---------------- flash attention (round-8 proven structure): SWAPPED QK^T, P in registers ----------------
// Sequential paired q-tiles (31-p then p) = uniform 33 iters/block; double-buffered
// global_load_lds K/V staging; fixed-max softmax in exp2 domain (cw pre-scaled by log2e);
// permlane P network; XCD-swizzled grid (each XCD serves 4 bh -> K/V L2-resident).
__global__ __launch_bounds__(256) void attn_kernel(const u16* __restrict__ Q,
                                                   const u16* __restrict__ K,
                                                   const u16* __restrict__ Vt,
                                                   const float* __restrict__ cw,
                                                   u16* __restrict__ O) {
  __shared__ u16 Kls[2][KVBLK * 64];
  __shared__ u16 Vls[2][64 * KVBLK];
  int flat = blockIdx.y * gridDim.x + blockIdx.x;  // grid (16, 32) = 512
  int swz = (flat & 7) * 64 + (flat >> 3);         // bijective, bh-contiguous per XCD
  int pidx = swz & 15, bh = swz >> 4;
  int tid = threadIdx.x;
  int lane = tid & 63, w = tid >> 6;
  int lr = lane & 15, lg = lane >> 4;
  const u16* Qh = Q + (size_t)bh * NN * HDD;
  const u16* Kh = K + (size_t)bh * NN * HDD;
  const u16* Vh = Vt + (size_t)bh * HDD * NN;
  const float* ch = cw + bh * NN;   // pre-scaled by log2e
  int b = bh >> 4, h = bh & 15;

  const float SCL = 0.125f * LOG2E;

  // staging: 512 slots of 16B per 8KB tile; LDS linear at slot*16B;
  // swizzle folded into SOURCE chunk: chunk ^ (row&7).
  int s0 = tid, s1 = tid + 256;
  int r0 = s0 >> 3, p0 = s0 & 7;
  int r1 = s1 >> 3, p1 = s1 & 7;
  const u16* gk0 = &Kh[(size_t)r0 * HDD + ((p0 ^ (r0 & 7)) * 8)];
  const u16* gk1 = &Kh[(size_t)r1 * HDD + ((p1 ^ (r1 & 7)) * 8)];
  const u16* gv0 = &Vh[(size_t)r0 * NN + ((p0 ^ (r0 & 7)) * 8)];
  const u16* gv1 = &Vh[(size_t)r1 * NN + ((p1 ^ (r1 & 7)) * 8)];

  for (int which = 0; which < 2; which++) {
    int tile = which == 0 ? (31 - pidx) : pidx;
    int qb = tile * QBLK + w * 16;
    int iq = qb + lr;  // this lane's q-row

    bf16x8_t qf[2];
#pragma unroll
    for (int s = 0; s < 2; s++)
      qf[s] = *(const bf16x8_t*)&Qh[(size_t)iq * HDD + s * 32 + lg * 8];
    float cq = ch[iq];

    float lsum = 0.f;
    f32x4_t oacc[4];
#pragma unroll
    for (int fn = 0; fn < 4; fn++) oacc[fn] = (f32x4_t){0.f, 0.f, 0.f, 0.f};

    // prologue: stage kv tile 0 into buffer 0
    async_copy16(gk0, &Kls[0][s0 * 8]);
    async_copy16(gk1, &Kls[0][s1 * 8]);
    async_copy16(gv0, &Vls[0][s0 * 8]);
    async_copy16(gv1, &Vls[0][s1 * 8]);
    __syncthreads();

    int cur = 0;
    for (int kvt = 0; kvt <= tile; kvt++) {
      // stage next tile into the other buffer BEFORE computing this one
      if (kvt < tile) {
        int nb = cur ^ 1;
        size_t kvn = (size_t)(kvt + 1) * KVBLK;
        async_copy16(gk0 + kvn * HDD, &Kls[nb][s0 * 8]);
        async_copy16(gk1 + kvn * HDD, &Kls[nb][s1 * 8]);
        async_copy16(gv0 + kvn, &Vls[nb][s0 * 8]);
        async_copy16(gv1 + kvn, &Vls[nb][s1 * 8]);
      }
      int kv0 = kvt * KVBLK;
      const u16* Kb = Kls[cur];
      const u16* Vb = Vls[cur];
      float4 ckv[4];
#pragma unroll
      for (int f = 0; f < 4; f++)
        ckv[f] = *(const float4*)&ch[kv0 + f * 16 + lg * 4];

      // S^T = K . Q^T : lane holds col i=lr, rows j = kv0 + f*16 + lg*4 + r
      f32x4_t sacc[4];
#pragma unroll
      for (int f = 0; f < 4; f++) sacc[f] = (f32x4_t){0.f, 0.f, 0.f, 0.f};
      __builtin_amdgcn_s_setprio(1);
#pragma unroll
      for (int f = 0; f < 4; f++) {
        int row = f * 16 + lr;
#pragma unroll
        for (int s = 0; s < 2; s++) {
          int boff = (row * 128 + s * 64 + lg * 16) ^ ((row & 7) << 4);
          bf16x8_t kf = *(const bf16x8_t*)((const char*)Kb + boff);
          sacc[f] = __builtin_amdgcn_mfma_f32_16x16x32_bf16(kf, qf[s], sacc[f], 0, 0, 0);
        }
      }
      __builtin_amdgcn_s_setprio(0);

      // fixed-max softmax in exp2 domain: e = exp2(s*scl + cq - ck); scalar lsum
      bool diag = (kvt == tile);
      float pv[4][4];
#pragma unroll
      for (int f = 0; f < 4; f++) {
        const float* ckp = &ckv[f].x;
#pragma unroll
        for (int r = 0; r < 4; r++) {
          float val = fmaf(sacc[f][r], SCL, cq - ckp[r]);
          float e = exp2f(val);
          if (diag && (kv0 + f * 16 + lg * 4 + r) > iq) e = 0.f;
          pv[f][r] = e; lsum += e;
        }
      }

      // pack P to bf16 pairs + permlane network -> B-fragments in regs
      bf16x8_t pa[2];
      make_pa(pv, pa);

      // O^T += V^T . P
      __builtin_amdgcn_s_setprio(1);
#pragma unroll
      for (int fn = 0; fn < 4; fn++) {
        int row = fn * 16 + lr;
#pragma unroll
        for (int s = 0; s < 2; s++) {
          int boff = (row * 128 + s * 64 + lg * 16) ^ ((row & 7) << 4);
          bf16x8_t vf = *(const bf16x8_t*)((const char*)Vb + boff);
          oacc[fn] = __builtin_amdgcn_mfma_f32_16x16x32_bf16(vf, pa[s], oacc[fn], 0, 0, 0);
        }
      }
      __builtin_amdgcn_s_setprio(0);
      __syncthreads();
      cur ^= 1;
    }

    // l-reduce over the 4 lanes sharing lr
    lsum += __shfl_xor(lsum, 16, 64);
    lsum += __shfl_xor(lsum, 32, 64);
    float rinv = 1.0f / lsum;

    // output: lane's q-row iq, hd = fn*16 + lg*4 + r -> packed 8B stores
    u16* orow = O + ((size_t)(b * NN + iq)) * DD + h * HDD;
#pragma unroll
    for (int fn = 0; fn < 4; fn++) {
      ushort4 o4;
      o4.x = f2bf(oacc[fn][0] * rinv);
      o4.y = f2bf(oacc[fn][1] * rinv);
      o4.z = f2bf(oacc[fn][2] * rinv);
      o4.w = f2bf(oacc[fn][3] * rinv);
      *(ushort4*)&orow[fn * 16 + lg * 4] = o4;
    }
  }
}

extern "C" void kernel_launch(void* const* d_in, const int* in_sizes, int n_in,
                              void* d_out, int out_size, void* d_ws, size_t ws_size,
                              hipStream_t stream) {
  const float* x  = (const float*)d_in[0];
  const float* Wq = (const float*)d_in[1];
  const float* Wk = (const float*)d_in[2];
  const float* Wv = (const float*)d_in[3];
  const float* Wo = (const float*)d_in[4];
  const float* Wf = (const float*)d_in[5];
  float* out = (float*)d_out;
  char* ws = (char*)d_ws;
  const size_t MB = 1024 * 1024;
  u16* x_bf  = (u16*)(ws + 0);        // 8 MB
  u16* WqkvT = (u16*)(ws + 8 * MB);   // 6 MB: WqT | WkT | WvT contiguous [3072][1024]
  u16* Qw    = (u16*)(ws + 16 * MB);  // 8 MB [bh][n][hd]
  u16* Kw    = (u16*)(ws + 24 * MB);  // 8 MB
  u16* Vw    = (u16*)(ws + 32 * MB);  // 8 MB [bh][hd][n] (written transposed by gemm)
  u16* Ow    = (u16*)(ws + 40 * MB);  // 8 MB [b n d]
  float* lf  = (float*)(ws + 48 * MB);            // 256 KB
  float* cwp = (float*)(ws + 48 * MB + 262144);   // 256 KB (pre-scaled by log2e)

  transpose_w_kernel<<<dim3(256, 4), 256, 0, stream>>>(Wq, Wk, Wv, Wo, WqkvT);
  logf_kernel<<<4096, 256, 0, stream>>>(x, Wf, lf, x_bf);
  cumsum_kernel<<<32, 64, 0, stream>>>(lf, cwp);
  // fused QKV GEMM: N = 3072; V written directly transposed
  gemm_kernel<<<dim3(24, 32), 512, 0, stream>>>(x_bf, WqkvT, Qw, Kw, Vw, nullptr, 0);
  attn_kernel<<<dim3(16, 32), 256, 0, stream>>>(Qw, Kw, Vw, cwp, Ow);
  gemm_kernel<<<dim3(8, 32), 512, 0, stream>>>(Ow, WqkvT + (size_t)3 * DD * DD, nullptr, nullptr, nullptr, out, 1);
}

// Round 14
// 125.864 us; speedup vs baseline: 1.2252x; 1.0539x over previous
//
#include <hip/hip_runtime.h>
#include <hip/hip_bf16.h>
#include <stdint.h>

#define NN 2048
#define DD 1024
#define HH 16
#define HDD 64
#define QBLK 64
#define KVBLK 64

typedef unsigned short u16;
typedef __attribute__((ext_vector_type(8))) __bf16 bf16x8_t;
typedef __attribute__((ext_vector_type(4))) float f32x4_t;

static __device__ __forceinline__ u16 f2bf(float f) {
  union { float f; uint32_t u; } v; v.f = f;
  uint32_t r = v.u + 0x7FFFu + ((v.u >> 16) & 1u);
  return (u16)(r >> 16);
}

static __device__ __forceinline__ uint32_t packbf2(float a, float b) {
  __hip_bfloat162 h2 = __float22bfloat162_rn(make_float2(a, b));
  union { __hip_bfloat162 hh; uint32_t u; } cvt; cvt.hh = h2;
  return cvt.u;
}

// async global->LDS, 16B per lane. LDS dest must be wave-uniform base + lane*16.
static __device__ __forceinline__ void async_copy16(const void* g, void* l) {
  __builtin_amdgcn_global_load_lds((const __attribute__((address_space(1))) void*)g,
                                   (__attribute__((address_space(3))) void*)l, 16, 0, 0);
}

// ---------------- weight transpose+cast: Wt[n][k] = W[k][n], 4 weights in one launch ----------------
__global__ void transpose_w_kernel(const float* __restrict__ W0, const float* __restrict__ W1,
                                   const float* __restrict__ W2, const float* __restrict__ W3,
                                   u16* __restrict__ Wt) {
  __shared__ float tile[64][65];
  const float* W = blockIdx.y == 0 ? W0 : blockIdx.y == 1 ? W1 : blockIdx.y == 2 ? W2 : W3;
  u16* out = Wt + (size_t)blockIdx.y * DD * DD;
  int bx = blockIdx.x & 15;   // n tile
  int by = blockIdx.x >> 4;   // k tile
  int t = threadIdx.x;
  int c = t & 63, r4 = t >> 6;
#pragma unroll
  for (int i = 0; i < 16; i++) {
    int row = i * 4 + r4;
    tile[row][c] = W[(by * 64 + row) * DD + bx * 64 + c];
  }
  __syncthreads();
#pragma unroll
  for (int i = 0; i < 16; i++) {
    int row = i * 4 + r4;
    out[(bx * 64 + row) * DD + by * 64 + c] = f2bf(tile[c][row]);
  }
}

// ---------------- log-sigmoid gate + fused x->bf16 cast ----------------
__global__ void logf_kernel(const float* __restrict__ x, const float* __restrict__ Wf,
                            float* __restrict__ lf, u16* __restrict__ xb) {
  __shared__ float xs[DD];
  __shared__ float part[16][17];
  int row = blockIdx.x;   // b*N + n
  int t = threadIdx.x;    // 256
  float4 v = *(const float4*)&x[(size_t)row * DD + t * 4];
  *(float4*)&xs[t * 4] = v;
  ushort4 o;
  o.x = f2bf(v.x); o.y = f2bf(v.y); o.z = f2bf(v.z); o.w = f2bf(v.w);
  *(ushort4*)&xb[(size_t)row * DD + t * 4] = o;
  __syncthreads();
  int h = t & 15, chunk = t >> 4;
  float s = 0.f;
#pragma unroll 8
  for (int e = 0; e < 64; e++)
    s += xs[chunk * 64 + e] * Wf[(chunk * 64 + e) * HH + h];
  part[chunk][h] = s;
  __syncthreads();
  if (t < 16) {
    float z = 0.f;
#pragma unroll
    for (int i = 0; i < 16; i++) z += part[i][t];
    float ls = fminf(z, 0.f) - log1pf(__expf(-fabsf(z)));
    int b = row >> 11, n = row & (NN - 1);
    lf[(b * HH + t) * NN + n] = ls;
  }
}

// ---------------- cumsum over n per (b,h): float4/lane, 8 outer iters ----------------
__global__ void cumsum_kernel(const float* __restrict__ lf, float* __restrict__ c) {
  int bh = blockIdx.x;
  int lane = threadIdx.x;  // 64
  const float* in = lf + bh * NN;
  float* out = c + bh * NN;
  float carry = 0.f;
  for (int t0 = 0; t0 < NN; t0 += 256) {
    float4 v = *(const float4*)&in[t0 + lane * 4];
    float s1 = v.x + v.y, s2 = s1 + v.z, s3 = s2 + v.w;
    float incl = s3;
#pragma unroll
    for (int off = 1; off < 64; off <<= 1) {
      float u = __shfl_up(incl, off, 64);
      if (lane >= off) incl += u;
    }
    float excl = incl - s3 + carry;
    float4 o;
    o.x = excl + v.x; o.y = excl + s1; o.z = excl + s2; o.w = excl + s3;
    *(float4*)&out[t0 + lane * 4] = o;
    carry = __shfl(incl, 63, 64) + carry;
  }
}

// ---------------- GEMM 128x128 tile, BK=64, swizzled LDS, 512 threads (8 waves, 2x4) ----------------
// mode 0 (QKV fused): Wt is [3072][1024]; Q/K -> [bh][n][hd] bf16; V -> [bh][hd][n] bf16 (fused transpose)
// mode 1 (output):    Wt is [1024][1024]; fp32 flat to oF
__global__ __launch_bounds__(512, 4) void gemm_kernel(const u16* __restrict__ A,
                                                      const u16* __restrict__ Wt,
                                                      u16* __restrict__ oQ, u16* __restrict__ oK,
                                                      u16* __restrict__ oV, float* __restrict__ oF,
                                                      int mode) {
  __shared__ u16 Als[128 * 64];
  __shared__ u16 Bls[128 * 64];
  int m0 = blockIdx.y * 128, n0 = blockIdx.x * 128;
  int tid = threadIdx.x;
  int lane = tid & 63, w = tid >> 6;   // 8 waves
  int wm = w >> 2, wn = w & 3;         // 2 x 4 wave grid: 64 rows x 32 cols each
  int lr = lane & 15, lg = lane >> 4;

  const u16* gA[2]; const u16* gB[2]; u16* lA[2]; u16* lB[2];
#pragma unroll
  for (int j = 0; j < 2; j++) {
    int s = tid + j * 512;
    int row = s >> 3, ch = s & 7;
    int scol = (ch ^ (row & 7)) * 8;
    gA[j] = &A [(size_t)(m0 + row) * DD + scol];
    gB[j] = &Wt[(size_t)(n0 + row) * DD + scol];
    lA[j] = &Als[s * 8];
    lB[j] = &Bls[s * 8];
  }

  f32x4_t acc[4][2];
#pragma unroll
  for (int i = 0; i < 4; i++)
#pragma unroll
    for (int j = 0; j < 2; j++) acc[i][j] = (f32x4_t){0.f, 0.f, 0.f, 0.f};

  for (int kt = 0; kt < DD; kt += 64) {
    __syncthreads();
#pragma unroll
    for (int j = 0; j < 2; j++) {
      async_copy16(gA[j] + kt, lA[j]);
      async_copy16(gB[j] + kt, lB[j]);
    }
    __syncthreads();
#pragma unroll
    for (int kk = 0; kk < 2; kk++) {
      bf16x8_t af[4], bfv[2];
#pragma unroll
      for (int mi = 0; mi < 4; mi++) {
        int row = wm * 64 + mi * 16 + lr;
        int boff = (row * 128 + kk * 64 + lg * 16) ^ ((row & 7) << 4);
        af[mi] = *(const bf16x8_t*)((const char*)Als + boff);
      }
#pragma unroll
      for (int ni = 0; ni < 2; ni++) {
        int row = wn * 32 + ni * 16 + lr;
        int boff = (row * 128 + kk * 64 + lg * 16) ^ ((row & 7) << 4);
        bfv[ni] = *(const bf16x8_t*)((const char*)Bls + boff);
      }
#pragma unroll
      for (int mi = 0; mi < 4; mi++)
#pragma unroll
        for (int ni = 0; ni < 2; ni++)
          acc[mi][ni] = __builtin_amdgcn_mfma_f32_16x16x32_bf16(af[mi], bfv[ni], acc[mi][ni], 0, 0, 0);
    }
  }

  if (mode == 1) {
#pragma unroll
    for (int mi = 0; mi < 4; mi++)
#pragma unroll
      for (int ni = 0; ni < 2; ni++) {
        int gcol = n0 + wn * 32 + ni * 16 + lr;
#pragma unroll
        for (int r = 0; r < 4; r++) {
          int grow = m0 + wm * 64 + mi * 16 + lg * 4 + r;
          oF[(size_t)grow * DD + gcol] = acc[mi][ni][r];
        }
      }
  } else {
    int which = n0 >> 10;
    int nl0 = n0 & 1023;
    if (which == 2) {
      // V: write transposed [bh][hd][n] -- 4 consecutive n per thread = packed 8B store
#pragma unroll
      for (int mi = 0; mi < 4; mi++)
#pragma unroll
        for (int ni = 0; ni < 2; ni++) {
          int gcol = nl0 + wn * 32 + ni * 16 + lr;
          int h = gcol >> 6, hd = gcol & 63;
          int grow0 = m0 + wm * 64 + mi * 16 + lg * 4;
          int b = grow0 >> 11, n = grow0 & (NN - 1);
          ushort4 o4;
          o4.x = f2bf(acc[mi][ni][0]);
          o4.y = f2bf(acc[mi][ni][1]);
          o4.z = f2bf(acc[mi][ni][2]);
          o4.w = f2bf(acc[mi][ni][3]);
          *(ushort4*)&oV[((size_t)(b * HH + h) * HDD + hd) * NN + n] = o4;
        }
    } else {
      u16* outp = which == 0 ? oQ : oK;
#pragma unroll
      for (int mi = 0; mi < 4; mi++)
#pragma unroll
        for (int ni = 0; ni < 2; ni++) {
          int gcol = nl0 + wn * 32 + ni * 16 + lr;
          int h = gcol >> 6, hd = gcol & 63;
#pragma unroll
          for (int r = 0; r < 4; r++) {
            int grow = m0 + wm * 64 + mi * 16 + lg * 4 + r;
            int b = grow >> 11, n = grow & (NN - 1);
            outp[((size_t)(b * HH + h) * NN + n) * HDD + hd] = f2bf(acc[mi][ni][r]);
          }
        }
    }
  }
}

// ---------------- flash attention (round-8 proven body, bit-exact): SWAPPED QK^T, P in registers ----------------
// Sequential paired q-tiles (31-p then p) = uniform 33 iters/block; double-buffered
// global_load_lds K/V staging; fixed-max softmax with __expf (NOT libm exp2f -- that
// emits slow-path VALU, +27% VALUBusy, r13 lesson); inline permlane P network;
// XCD-swizzled grid (each XCD serves 4 bh -> K/V L2-resident).
__global__ __launch_bounds__(256) void attn_kernel(const u16* __restrict__ Q,
                                                   const u16* __restrict__ K,
                                                   const u16* __restrict__ Vt,
                                                   const float* __restrict__ cw,
                                                   u16* __restrict__ O) {
  __shared__ u16 Kls[2][KVBLK * 64];
  __shared__ u16 Vls[2][64 * KVBLK];
  int flat = blockIdx.y * gridDim.x + blockIdx.x;  // grid (16, 32) = 512
  int swz = (flat & 7) * 64 + (flat >> 3);         // bijective, bh-contiguous per XCD
  int pidx = swz & 15, bh = swz >> 4;
  int tid = threadIdx.x;
  int lane = tid & 63, w = tid >> 6;
  int lr = lane & 15, lg = lane >> 4;
  const u16* Qh = Q + (size_t)bh * NN * HDD;
  const u16* Kh = K + (size_t)bh * NN * HDD;
  const u16* Vh = Vt + (size_t)bh * HDD * NN;
  const float* ch = cw + bh * NN;
  int b = bh >> 4, h = bh & 15;

  // staging: 512 slots of 16B per 8KB tile; LDS linear at slot*16B;
  // swizzle folded into SOURCE chunk: chunk ^ (row&7).
  int s0 = tid, s1 = tid + 256;
  int r0 = s0 >> 3, p0 = s0 & 7;
  int r1 = s1 >> 3, p1 = s1 & 7;
  const u16* gk0 = &Kh[(size_t)r0 * HDD + ((p0 ^ (r0 & 7)) * 8)];
  const u16* gk1 = &Kh[(size_t)r1 * HDD + ((p1 ^ (r1 & 7)) * 8)];
  const u16* gv0 = &Vh[(size_t)r0 * NN + ((p0 ^ (r0 & 7)) * 8)];
  const u16* gv1 = &Vh[(size_t)r1 * NN + ((p1 ^ (r1 & 7)) * 8)];

  for (int which = 0; which < 2; which++) {
    int tile = which == 0 ? (31 - pidx) : pidx;
    int qb = tile * QBLK + w * 16;
    int iq = qb + lr;  // this lane's q-row

    bf16x8_t qf[2];
#pragma unroll
    for (int s = 0; s < 2; s++)
      qf[s] = *(const bf16x8_t*)&Qh[(size_t)iq * HDD + s * 32 + lg * 8];
    float cq = ch[iq];

    float lsum = 0.f;
    f32x4_t oacc[4];
#pragma unroll
    for (int fn = 0; fn < 4; fn++) oacc[fn] = (f32x4_t){0.f, 0.f, 0.f, 0.f};

    // prologue: stage kv tile 0 into buffer 0
    async_copy16(gk0, &Kls[0][s0 * 8]);
    async_copy16(gk1, &Kls[0][s1 * 8]);
    async_copy16(gv0, &Vls[0][s0 * 8]);
    async_copy16(gv1, &Vls[0][s1 * 8]);
    __syncthreads();

    int cur = 0;
    for (int kvt = 0; kvt <= tile; kvt++) {
      // stage next tile into the other buffer BEFORE computing this one
      if (kvt < tile) {
        int nb = cur ^ 1;
        size_t kvn = (size_t)(kvt + 1) * KVBLK;
        async_copy16(gk0 + kvn * HDD, &Kls[nb][s0 * 8]);
        async_copy16(gk1 + kvn * HDD, &Kls[nb][s1 * 8]);
        async_copy16(gv0 + kvn, &Vls[nb][s0 * 8]);
        async_copy16(gv1 + kvn, &Vls[nb][s1 * 8]);
      }
      int kv0 = kvt * KVBLK;
      const u16* Kb = Kls[cur];
      const u16* Vb = Vls[cur];
      float4 ckv[4];
#pragma unroll
      for (int f = 0; f < 4; f++)
        ckv[f] = *(const float4*)&ch[kv0 + f * 16 + lg * 4];

      // S^T = K . Q^T : lane holds col i=lr, rows j = kv0 + f*16 + lg*4 + r
      f32x4_t sacc[4];
#pragma unroll
      for (int f = 0; f < 4; f++) sacc[f] = (f32x4_t){0.f, 0.f, 0.f, 0.f};
      __builtin_amdgcn_s_setprio(1);
#pragma unroll
      for (int f = 0; f < 4; f++) {
        int row = f * 16 + lr;
#pragma unroll
        for (int s = 0; s < 2; s++) {
          int boff = (row * 128 + s * 64 + lg * 16) ^ ((row & 7) << 4);
          bf16x8_t kf = *(const bf16x8_t*)((const char*)Kb + boff);
          sacc[f] = __builtin_amdgcn_mfma_f32_16x16x32_bf16(kf, qf[s], sacc[f], 0, 0, 0);
        }
      }
      __builtin_amdgcn_s_setprio(0);

      // fixed-max softmax: e = __expf(s*scale + cq - ck); scalar lsum
      bool diag = (kvt == tile);
      float pv[4][4];
#pragma unroll
      for (int f = 0; f < 4; f++) {
        const float* ckp = &ckv[f].x;
#pragma unroll
        for (int r = 0; r < 4; r++) {
          float val = fmaf(sacc[f][r], 0.125f, cq - ckp[r]);
          float e = __expf(val);
          if (diag && (kv0 + f * 16 + lg * 4 + r) > iq) e = 0.f;
          pv[f][r] = e; lsum += e;
        }
      }

      // pack P quarters to bf16 pairs: wq[f][0] = (r0,r1), wq[f][1] = (r2,r3)
      uint32_t wq[4][2];
#pragma unroll
      for (int f = 0; f < 4; f++) {
        wq[f][0] = packbf2(pv[f][0], pv[f][1]);
        wq[f][1] = packbf2(pv[f][2], pv[f][3]);
      }
      // permlane network: pa[s] words = {c0,c1,c2,c3}; s-half uses f = 2s, 2s+1
      bf16x8_t pa[2];
#pragma unroll
      for (int s = 0; s < 2; s++) {
        uint32_t x0 = wq[2 * s][0], x1 = wq[2 * s][1];
        uint32_t y0 = wq[2 * s + 1][0], y1 = wq[2 * s + 1][1];
        asm volatile("v_permlane32_swap_b32 %0, %1" : "+v"(x0), "+v"(y0));
        asm volatile("v_permlane32_swap_b32 %0, %1" : "+v"(x1), "+v"(y1));
        asm volatile("v_permlane16_swap_b32 %0, %1" : "+v"(x0), "+v"(y0));
        asm volatile("v_permlane16_swap_b32 %0, %1" : "+v"(x1), "+v"(y1));
        union { uint32_t u[4]; bf16x8_t v; } pk;
        pk.u[0] = x0; pk.u[1] = x1; pk.u[2] = y0; pk.u[3] = y1;
        pa[s] = pk.v;
      }

      // O^T += V^T . P
      __builtin_amdgcn_s_setprio(1);
#pragma unroll
      for (int fn = 0; fn < 4; fn++) {
        int row = fn * 16 + lr;
#pragma unroll
        for (int s = 0; s < 2; s++) {
          int boff = (row * 128 + s * 64 + lg * 16) ^ ((row & 7) << 4);
          bf16x8_t vf = *(const bf16x8_t*)((const char*)Vb + boff);
          oacc[fn] = __builtin_amdgcn_mfma_f32_16x16x32_bf16(vf, pa[s], oacc[fn], 0, 0, 0);
        }
      }
      __builtin_amdgcn_s_setprio(0);
      __syncthreads();
      cur ^= 1;
    }

    // l-reduce over the 4 lanes sharing lr
    lsum += __shfl_xor(lsum, 16, 64);
    lsum += __shfl_xor(lsum, 32, 64);
    float rinv = 1.0f / lsum;

    // output: lane's q-row iq, hd = fn*16 + lg*4 + r -> packed 8B stores
    u16* orow = O + ((size_t)(b * NN + iq)) * DD + h * HDD;
#pragma unroll
    for (int fn = 0; fn < 4; fn++) {
      ushort4 o4;
      o4.x = f2bf(oacc[fn][0] * rinv);
      o4.y = f2bf(oacc[fn][1] * rinv);
      o4.z = f2bf(oacc[fn][2] * rinv);
      o4.w = f2bf(oacc[fn][3] * rinv);
      *(ushort4*)&orow[fn * 16 + lg * 4] = o4;
    }
  }
}

extern "C" void kernel_launch(void* const* d_in, const int* in_sizes, int n_in,
                              void* d_out, int out_size, void* d_ws, size_t ws_size,
                              hipStream_t stream) {
  const float* x  = (const float*)d_in[0];
  const float* Wq = (const float*)d_in[1];
  const float* Wk = (const float*)d_in[2];
  const float* Wv = (const float*)d_in[3];
  const float* Wo = (const float*)d_in[4];
  const float* Wf = (const float*)d_in[5];
  float* out = (float*)d_out;
  char* ws = (char*)d_ws;
  const size_t MB = 1024 * 1024;
  u16* x_bf  = (u16*)(ws + 0);        // 8 MB
  u16* WqkvT = (u16*)(ws + 8 * MB);   // 6 MB: WqT | WkT | WvT contiguous [3072][1024]
  u16* Qw    = (u16*)(ws + 16 * MB);  // 8 MB [bh][n][hd]
  u16* Kw    = (u16*)(ws + 24 * MB);  // 8 MB
  u16* Vw    = (u16*)(ws + 32 * MB);  // 8 MB [bh][hd][n] (written transposed by gemm)
  u16* Ow    = (u16*)(ws + 40 * MB);  // 8 MB [b n d]
  float* lf  = (float*)(ws + 48 * MB);            // 256 KB
  float* cwp = (float*)(ws + 48 * MB + 262144);   // 256 KB

  transpose_w_kernel<<<dim3(256, 4), 256, 0, stream>>>(Wq, Wk, Wv, Wo, WqkvT);
  logf_kernel<<<4096, 256, 0, stream>>>(x, Wf, lf, x_bf);
  cumsum_kernel<<<32, 64, 0, stream>>>(lf, cwp);
  // fused QKV GEMM: N = 3072; V written directly transposed
  gemm_kernel<<<dim3(24, 32), 512, 0, stream>>>(x_bf, WqkvT, Qw, Kw, Vw, nullptr, 0);
  attn_kernel<<<dim3(16, 32), 256, 0, stream>>>(Qw, Kw, Vw, cwp, Ow);
  gemm_kernel<<<dim3(8, 32), 512, 0, stream>>>(Ow, WqkvT + (size_t)3 * DD * DD, nullptr, nullptr, nullptr, out, 1);
}

// Round 15
// 120.380 us; speedup vs baseline: 1.2811x; 1.0456x over previous
//
#include <hip/hip_runtime.h>
#include <hip/hip_bf16.h>
#include <stdint.h>

#define NN 2048
#define DD 1024
#define HH 16
#define HDD 64
#define QBLK 64
#define KVBLK 64

typedef unsigned short u16;
typedef __attribute__((ext_vector_type(8))) __bf16 bf16x8_t;
typedef __attribute__((ext_vector_type(4))) float f32x4_t;

static __device__ __forceinline__ u16 f2bf(float f) {
  union { float f; uint32_t u; } v; v.f = f;
  uint32_t r = v.u + 0x7FFFu + ((v.u >> 16) & 1u);
  return (u16)(r >> 16);
}

static __device__ __forceinline__ uint32_t packbf2(float a, float b) {
  __hip_bfloat162 h2 = __float22bfloat162_rn(make_float2(a, b));
  union { __hip_bfloat162 hh; uint32_t u; } cvt; cvt.hh = h2;
  return cvt.u;
}

// async global->LDS, 16B per lane. LDS dest must be wave-uniform base + lane*16.
static __device__ __forceinline__ void async_copy16(const void* g, void* l) {
  __builtin_amdgcn_global_load_lds((const __attribute__((address_space(1))) void*)g,
                                   (__attribute__((address_space(3))) void*)l, 16, 0, 0);
}

// ---------------- fused prep: logf (blocks 0..4095) + weight transpose (blocks 4096..5119) ----------------
// logf: per-row log-sigmoid gate + x->bf16 cast. transpose: Wt[n][k] = W[k][n] for 4 weights.
__global__ void prep_kernel(const float* __restrict__ x, const float* __restrict__ Wf,
                            float* __restrict__ lf, u16* __restrict__ xb,
                            const float* __restrict__ W0, const float* __restrict__ W1,
                            const float* __restrict__ W2, const float* __restrict__ W3,
                            u16* __restrict__ Wt) {
  __shared__ float xs[DD];
  __shared__ float part[16][17];
  __shared__ float tile[64][65];
  int t = threadIdx.x;  // 256
  if (blockIdx.x < 4096) {
    int row = blockIdx.x;   // b*N + n
    float4 v = *(const float4*)&x[(size_t)row * DD + t * 4];
    *(float4*)&xs[t * 4] = v;
    ushort4 o;
    o.x = f2bf(v.x); o.y = f2bf(v.y); o.z = f2bf(v.z); o.w = f2bf(v.w);
    *(ushort4*)&xb[(size_t)row * DD + t * 4] = o;
    __syncthreads();
    int h = t & 15, chunk = t >> 4;
    float s = 0.f;
#pragma unroll 8
    for (int e = 0; e < 64; e++)
      s += xs[chunk * 64 + e] * Wf[(chunk * 64 + e) * HH + h];
    part[chunk][h] = s;
    __syncthreads();
    if (t < 16) {
      float z = 0.f;
#pragma unroll
      for (int i = 0; i < 16; i++) z += part[i][t];
      float ls = fminf(z, 0.f) - log1pf(__expf(-fabsf(z)));
      int b = row >> 11, n = row & (NN - 1);
      lf[(b * HH + t) * NN + n] = ls;
    }
  } else {
    int bid = blockIdx.x - 4096;
    int wq = bid >> 8;  // which weight
    const float* W = wq == 0 ? W0 : wq == 1 ? W1 : wq == 2 ? W2 : W3;
    u16* out = Wt + (size_t)wq * DD * DD;
    int bx = bid & 15;          // n tile
    int by = (bid >> 4) & 15;   // k tile
    int c = t & 63, r4 = t >> 6;
#pragma unroll
    for (int i = 0; i < 16; i++) {
      int row = i * 4 + r4;
      tile[row][c] = W[(by * 64 + row) * DD + bx * 64 + c];
    }
    __syncthreads();
#pragma unroll
    for (int i = 0; i < 16; i++) {
      int row = i * 4 + r4;
      out[(bx * 64 + row) * DD + by * 64 + c] = f2bf(tile[c][row]);
    }
  }
}

// ---------------- cumsum over n per (b,h): float4/lane, 8 outer iters ----------------
__global__ void cumsum_kernel(const float* __restrict__ lf, float* __restrict__ c) {
  int bh = blockIdx.x;
  int lane = threadIdx.x;  // 64
  const float* in = lf + bh * NN;
  float* out = c + bh * NN;
  float carry = 0.f;
  for (int t0 = 0; t0 < NN; t0 += 256) {
    float4 v = *(const float4*)&in[t0 + lane * 4];
    float s1 = v.x + v.y, s2 = s1 + v.z, s3 = s2 + v.w;
    float incl = s3;
#pragma unroll
    for (int off = 1; off < 64; off <<= 1) {
      float u = __shfl_up(incl, off, 64);
      if (lane >= off) incl += u;
    }
    float excl = incl - s3 + carry;
    float4 o;
    o.x = excl + v.x; o.y = excl + s1; o.z = excl + s2; o.w = excl + s3;
    *(float4*)&out[t0 + lane * 4] = o;
    carry = __shfl(incl, 63, 64) + carry;
  }
}

// ---------------- QKV GEMM 128x128 tile, BK=64, swizzled LDS, 512 threads (8 waves, 2x4) ----------------
// Wt is [3072][1024]; Q/K -> [bh][n][hd] bf16; V -> [bh][hd][n] bf16 (fused transpose)
__global__ __launch_bounds__(512, 4) void gemm_kernel(const u16* __restrict__ A,
                                                      const u16* __restrict__ Wt,
                                                      u16* __restrict__ oQ, u16* __restrict__ oK,
                                                      u16* __restrict__ oV) {
  __shared__ u16 Als[128 * 64];
  __shared__ u16 Bls[128 * 64];
  int m0 = blockIdx.y * 128, n0 = blockIdx.x * 128;
  int tid = threadIdx.x;
  int lane = tid & 63, w = tid >> 6;   // 8 waves
  int wm = w >> 2, wn = w & 3;         // 2 x 4 wave grid: 64 rows x 32 cols each
  int lr = lane & 15, lg = lane >> 4;

  const u16* gA[2]; const u16* gB[2]; u16* lA[2]; u16* lB[2];
#pragma unroll
  for (int j = 0; j < 2; j++) {
    int s = tid + j * 512;
    int row = s >> 3, ch = s & 7;
    int scol = (ch ^ (row & 7)) * 8;
    gA[j] = &A [(size_t)(m0 + row) * DD + scol];
    gB[j] = &Wt[(size_t)(n0 + row) * DD + scol];
    lA[j] = &Als[s * 8];
    lB[j] = &Bls[s * 8];
  }

  f32x4_t acc[4][2];
#pragma unroll
  for (int i = 0; i < 4; i++)
#pragma unroll
    for (int j = 0; j < 2; j++) acc[i][j] = (f32x4_t){0.f, 0.f, 0.f, 0.f};

  for (int kt = 0; kt < DD; kt += 64) {
    __syncthreads();
#pragma unroll
    for (int j = 0; j < 2; j++) {
      async_copy16(gA[j] + kt, lA[j]);
      async_copy16(gB[j] + kt, lB[j]);
    }
    __syncthreads();
#pragma unroll
    for (int kk = 0; kk < 2; kk++) {
      bf16x8_t af[4], bfv[2];
#pragma unroll
      for (int mi = 0; mi < 4; mi++) {
        int row = wm * 64 + mi * 16 + lr;
        int boff = (row * 128 + kk * 64 + lg * 16) ^ ((row & 7) << 4);
        af[mi] = *(const bf16x8_t*)((const char*)Als + boff);
      }
#pragma unroll
      for (int ni = 0; ni < 2; ni++) {
        int row = wn * 32 + ni * 16 + lr;
        int boff = (row * 128 + kk * 64 + lg * 16) ^ ((row & 7) << 4);
        bfv[ni] = *(const bf16x8_t*)((const char*)Bls + boff);
      }
#pragma unroll
      for (int mi = 0; mi < 4; mi++)
#pragma unroll
        for (int ni = 0; ni < 2; ni++)
          acc[mi][ni] = __builtin_amdgcn_mfma_f32_16x16x32_bf16(af[mi], bfv[ni], acc[mi][ni], 0, 0, 0);
    }
  }

  int which = n0 >> 10;
  int nl0 = n0 & 1023;
  if (which == 2) {
    // V: write transposed [bh][hd][n] -- 4 consecutive n per thread = packed 8B store
#pragma unroll
    for (int mi = 0; mi < 4; mi++)
#pragma unroll
      for (int ni = 0; ni < 2; ni++) {
        int gcol = nl0 + wn * 32 + ni * 16 + lr;
        int h = gcol >> 6, hd = gcol & 63;
        int grow0 = m0 + wm * 64 + mi * 16 + lg * 4;
        int b = grow0 >> 11, n = grow0 & (NN - 1);
        ushort4 o4;
        o4.x = f2bf(acc[mi][ni][0]);
        o4.y = f2bf(acc[mi][ni][1]);
        o4.z = f2bf(acc[mi][ni][2]);
        o4.w = f2bf(acc[mi][ni][3]);
        *(ushort4*)&oV[((size_t)(b * HH + h) * HDD + hd) * NN + n] = o4;
      }
  } else {
    u16* outp = which == 0 ? oQ : oK;
#pragma unroll
    for (int mi = 0; mi < 4; mi++)
#pragma unroll
      for (int ni = 0; ni < 2; ni++) {
        int gcol = nl0 + wn * 32 + ni * 16 + lr;
        int h = gcol >> 6, hd = gcol & 63;
#pragma unroll
        for (int r = 0; r < 4; r++) {
          int grow = m0 + wm * 64 + mi * 16 + lg * 4 + r;
          int b = grow >> 11, n = grow & (NN - 1);
          outp[((size_t)(b * HH + h) * NN + n) * HDD + hd] = f2bf(acc[mi][ni][r]);
        }
      }
  }
}

// ---------------- out GEMM 128x64 tile, BK=64, grid 512 = 2 blocks/CU (overlap barrier stalls) ----------------
__global__ __launch_bounds__(512, 4) void gemm_out_kernel(const u16* __restrict__ A,
                                                          const u16* __restrict__ Wt,
                                                          float* __restrict__ oF) {
  __shared__ u16 Als[128 * 64];
  __shared__ u16 Bls[64 * 64];
  int m0 = blockIdx.y * 128, n0 = blockIdx.x * 64;
  int tid = threadIdx.x;
  int lane = tid & 63, w = tid >> 6;   // 8 waves
  int wm = w >> 2, wn = w & 3;         // 2 x 4 wave grid: 64 rows x 16 cols each
  int lr = lane & 15, lg = lane >> 4;

  const u16* gA[2]; u16* lA[2];
#pragma unroll
  for (int j = 0; j < 2; j++) {
    int s = tid + j * 512;
    int row = s >> 3, ch = s & 7;
    int scol = (ch ^ (row & 7)) * 8;
    gA[j] = &A[(size_t)(m0 + row) * DD + scol];
    lA[j] = &Als[s * 8];
  }
  int rowb = tid >> 3, chb = tid & 7;
  const u16* gB = &Wt[(size_t)(n0 + rowb) * DD + ((chb ^ (rowb & 7)) * 8)];
  u16* lB = &Bls[tid * 8];

  f32x4_t acc[4];
#pragma unroll
  for (int i = 0; i < 4; i++) acc[i] = (f32x4_t){0.f, 0.f, 0.f, 0.f};

  for (int kt = 0; kt < DD; kt += 64) {
    __syncthreads();
#pragma unroll
    for (int j = 0; j < 2; j++) async_copy16(gA[j] + kt, lA[j]);
    async_copy16(gB + kt, lB);
    __syncthreads();
#pragma unroll
    for (int kk = 0; kk < 2; kk++) {
      bf16x8_t af[4], bf1;
#pragma unroll
      for (int mi = 0; mi < 4; mi++) {
        int row = wm * 64 + mi * 16 + lr;
        int boff = (row * 128 + kk * 64 + lg * 16) ^ ((row & 7) << 4);
        af[mi] = *(const bf16x8_t*)((const char*)Als + boff);
      }
      {
        int row = wn * 16 + lr;
        int boff = (row * 128 + kk * 64 + lg * 16) ^ ((row & 7) << 4);
        bf1 = *(const bf16x8_t*)((const char*)Bls + boff);
      }
#pragma unroll
      for (int mi = 0; mi < 4; mi++)
        acc[mi] = __builtin_amdgcn_mfma_f32_16x16x32_bf16(af[mi], bf1, acc[mi], 0, 0, 0);
    }
  }

#pragma unroll
  for (int mi = 0; mi < 4; mi++) {
    int gcol = n0 + wn * 16 + lr;
#pragma unroll
    for (int r = 0; r < 4; r++) {
      int grow = m0 + wm * 64 + mi * 16 + lg * 4 + r;
      oF[(size_t)grow * DD + gcol] = acc[mi][r];
    }
  }
}

// ---------------- flash attention (round-8 proven body, bit-exact): SWAPPED QK^T, P in registers ----------------
// Sequential paired q-tiles (31-p then p) = uniform 33 iters/block; double-buffered
// global_load_lds K/V staging; fixed-max softmax with __expf (NOT libm exp2f -- that
// emits slow-path VALU, +27% VALUBusy, r13 lesson); inline permlane P network;
// XCD-swizzled grid (each XCD serves 4 bh -> K/V L2-resident).
__global__ __launch_bounds__(256) void attn_kernel(const u16* __restrict__ Q,
                                                   const u16* __restrict__ K,
                                                   const u16* __restrict__ Vt,
                                                   const float* __restrict__ cw,
                                                   u16* __restrict__ O) {
  __shared__ u16 Kls[2][KVBLK * 64];
  __shared__ u16 Vls[2][64 * KVBLK];
  int flat = blockIdx.y * gridDim.x + blockIdx.x;  // grid (16, 32) = 512
  int swz = (flat & 7) * 64 + (flat >> 3);         // bijective, bh-contiguous per XCD
  int pidx = swz & 15, bh = swz >> 4;
  int tid = threadIdx.x;
  int lane = tid & 63, w = tid >> 6;
  int lr = lane & 15, lg = lane >> 4;
  const u16* Qh = Q + (size_t)bh * NN * HDD;
  const u16* Kh = K + (size_t)bh * NN * HDD;
  const u16* Vh = Vt + (size_t)bh * HDD * NN;
  const float* ch = cw + bh * NN;
  int b = bh >> 4, h = bh & 15;

  // staging: 512 slots of 16B per 8KB tile; LDS linear at slot*16B;
  // swizzle folded into SOURCE chunk: chunk ^ (row&7).
  int s0 = tid, s1 = tid + 256;
  int r0 = s0 >> 3, p0 = s0 & 7;
  int r1 = s1 >> 3, p1 = s1 & 7;
  const u16* gk0 = &Kh[(size_t)r0 * HDD + ((p0 ^ (r0 & 7)) * 8)];
  const u16* gk1 = &Kh[(size_t)r1 * HDD + ((p1 ^ (r1 & 7)) * 8)];
  const u16* gv0 = &Vh[(size_t)r0 * NN + ((p0 ^ (r0 & 7)) * 8)];
  const u16* gv1 = &Vh[(size_t)r1 * NN + ((p1 ^ (r1 & 7)) * 8)];

  for (int which = 0; which < 2; which++) {
    int tile = which == 0 ? (31 - pidx) : pidx;
    int qb = tile * QBLK + w * 16;
    int iq = qb + lr;  // this lane's q-row

    bf16x8_t qf[2];
#pragma unroll
    for (int s = 0; s < 2; s++)
      qf[s] = *(const bf16x8_t*)&Qh[(size_t)iq * HDD + s * 32 + lg * 8];
    float cq = ch[iq];

    float lsum = 0.f;
    f32x4_t oacc[4];
#pragma unroll
    for (int fn = 0; fn < 4; fn++) oacc[fn] = (f32x4_t){0.f, 0.f, 0.f, 0.f};

    // prologue: stage kv tile 0 into buffer 0
    async_copy16(gk0, &Kls[0][s0 * 8]);
    async_copy16(gk1, &Kls[0][s1 * 8]);
    async_copy16(gv0, &Vls[0][s0 * 8]);
    async_copy16(gv1, &Vls[0][s1 * 8]);
    __syncthreads();

    int cur = 0;
    for (int kvt = 0; kvt <= tile; kvt++) {
      // stage next tile into the other buffer BEFORE computing this one
      if (kvt < tile) {
        int nb = cur ^ 1;
        size_t kvn = (size_t)(kvt + 1) * KVBLK;
        async_copy16(gk0 + kvn * HDD, &Kls[nb][s0 * 8]);
        async_copy16(gk1 + kvn * HDD, &Kls[nb][s1 * 8]);
        async_copy16(gv0 + kvn, &Vls[nb][s0 * 8]);
        async_copy16(gv1 + kvn, &Vls[nb][s1 * 8]);
      }
      int kv0 = kvt * KVBLK;
      const u16* Kb = Kls[cur];
      const u16* Vb = Vls[cur];
      float4 ckv[4];
#pragma unroll
      for (int f = 0; f < 4; f++)
        ckv[f] = *(const float4*)&ch[kv0 + f * 16 + lg * 4];

      // S^T = K . Q^T : lane holds col i=lr, rows j = kv0 + f*16 + lg*4 + r
      f32x4_t sacc[4];
#pragma unroll
      for (int f = 0; f < 4; f++) sacc[f] = (f32x4_t){0.f, 0.f, 0.f, 0.f};
      __builtin_amdgcn_s_setprio(1);
#pragma unroll
      for (int f = 0; f < 4; f++) {
        int row = f * 16 + lr;
#pragma unroll
        for (int s = 0; s < 2; s++) {
          int boff = (row * 128 + s * 64 + lg * 16) ^ ((row & 7) << 4);
          bf16x8_t kf = *(const bf16x8_t*)((const char*)Kb + boff);
          sacc[f] = __builtin_amdgcn_mfma_f32_16x16x32_bf16(kf, qf[s], sacc[f], 0, 0, 0);
        }
      }
      __builtin_amdgcn_s_setprio(0);

      // fixed-max softmax: e = __expf(s*scale + cq - ck); scalar lsum
      bool diag = (kvt == tile);
      float pv[4][4];
#pragma unroll
      for (int f = 0; f < 4; f++) {
        const float* ckp = &ckv[f].x;
#pragma unroll
        for (int r = 0; r < 4; r++) {
          float val = fmaf(sacc[f][r], 0.125f, cq - ckp[r]);
          float e = __expf(val);
          if (diag && (kv0 + f * 16 + lg * 4 + r) > iq) e = 0.f;
          pv[f][r] = e; lsum += e;
        }
      }

      // pack P quarters to bf16 pairs: wq[f][0] = (r0,r1), wq[f][1] = (r2,r3)
      uint32_t wq[4][2];
#pragma unroll
      for (int f = 0; f < 4; f++) {
        wq[f][0] = packbf2(pv[f][0], pv[f][1]);
        wq[f][1] = packbf2(pv[f][2], pv[f][3]);
      }
      // permlane network: pa[s] words = {c0,c1,c2,c3}; s-half uses f = 2s, 2s+1
      bf16x8_t pa[2];
#pragma unroll
      for (int s = 0; s < 2; s++) {
        uint32_t x0 = wq[2 * s][0], x1 = wq[2 * s][1];
        uint32_t y0 = wq[2 * s + 1][0], y1 = wq[2 * s + 1][1];
        asm volatile("v_permlane32_swap_b32 %0, %1" : "+v"(x0), "+v"(y0));
        asm volatile("v_permlane32_swap_b32 %0, %1" : "+v"(x1), "+v"(y1));
        asm volatile("v_permlane16_swap_b32 %0, %1" : "+v"(x0), "+v"(y0));
        asm volatile("v_permlane16_swap_b32 %0, %1" : "+v"(x1), "+v"(y1));
        union { uint32_t u[4]; bf16x8_t v; } pk;
        pk.u[0] = x0; pk.u[1] = x1; pk.u[2] = y0; pk.u[3] = y1;
        pa[s] = pk.v;
      }

      // O^T += V^T . P
      __builtin_amdgcn_s_setprio(1);
#pragma unroll
      for (int fn = 0; fn < 4; fn++) {
        int row = fn * 16 + lr;
#pragma unroll
        for (int s = 0; s < 2; s++) {
          int boff = (row * 128 + s * 64 + lg * 16) ^ ((row & 7) << 4);
          bf16x8_t vf = *(const bf16x8_t*)((const char*)Vb + boff);
          oacc[fn] = __builtin_amdgcn_mfma_f32_16x16x32_bf16(vf, pa[s], oacc[fn], 0, 0, 0);
        }
      }
      __builtin_amdgcn_s_setprio(0);
      __syncthreads();
      cur ^= 1;
    }

    // l-reduce over the 4 lanes sharing lr
    lsum += __shfl_xor(lsum, 16, 64);
    lsum += __shfl_xor(lsum, 32, 64);
    float rinv = 1.0f / lsum;

    // output: lane's q-row iq, hd = fn*16 + lg*4 + r -> packed 8B stores
    u16* orow = O + ((size_t)(b * NN + iq)) * DD + h * HDD;
#pragma unroll
    for (int fn = 0; fn < 4; fn++) {
      ushort4 o4;
      o4.x = f2bf(oacc[fn][0] * rinv);
      o4.y = f2bf(oacc[fn][1] * rinv);
      o4.z = f2bf(oacc[fn][2] * rinv);
      o4.w = f2bf(oacc[fn][3] * rinv);
      *(ushort4*)&orow[fn * 16 + lg * 4] = o4;
    }
  }
}

extern "C" void kernel_launch(void* const* d_in, const int* in_sizes, int n_in,
                              void* d_out, int out_size, void* d_ws, size_t ws_size,
                              hipStream_t stream) {
  const float* x  = (const float*)d_in[0];
  const float* Wq = (const float*)d_in[1];
  const float* Wk = (const float*)d_in[2];
  const float* Wv = (const float*)d_in[3];
  const float* Wo = (const float*)d_in[4];
  const float* Wf = (const float*)d_in[5];
  float* out = (float*)d_out;
  char* ws = (char*)d_ws;
  const size_t MB = 1024 * 1024;
  u16* x_bf  = (u16*)(ws + 0);        // 8 MB
  u16* WqkvT = (u16*)(ws + 8 * MB);   // 6 MB: WqT | WkT | WvT contiguous [3072][1024]; WoT follows
  u16* Qw    = (u16*)(ws + 16 * MB);  // 8 MB [bh][n][hd]
  u16* Kw    = (u16*)(ws + 24 * MB);  // 8 MB
  u16* Vw    = (u16*)(ws + 32 * MB);  // 8 MB [bh][hd][n] (written transposed by gemm)
  u16* Ow    = (u16*)(ws + 40 * MB);  // 8 MB [b n d]
  float* lf  = (float*)(ws + 48 * MB);            // 256 KB
  float* cwp = (float*)(ws + 48 * MB + 262144);   // 256 KB

  // fused prep: logf+cast (4096 blocks) || weight transpose (1024 blocks)
  prep_kernel<<<5120, 256, 0, stream>>>(x, Wf, lf, x_bf, Wq, Wk, Wv, Wo, WqkvT);
  cumsum_kernel<<<32, 64, 0, stream>>>(lf, cwp);
  // fused QKV GEMM: N = 3072; V written directly transposed
  gemm_kernel<<<dim3(24, 32), 512, 0, stream>>>(x_bf, WqkvT, Qw, Kw, Vw);
  attn_kernel<<<dim3(16, 32), 256, 0, stream>>>(Qw, Kw, Vw, cwp, Ow);
  gemm_out_kernel<<<dim3(16, 32), 512, 0, stream>>>(Ow, WqkvT + (size_t)3 * DD * DD, out);
}

// Round 16
// 118.606 us; speedup vs baseline: 1.3002x; 1.0150x over previous
//
#include <hip/hip_runtime.h>
#include <hip/hip_bf16.h>
#include <stdint.h>

#define NN 2048
#define DD 1024
#define HH 16
#define HDD 64
#define QBLK 64
#define KVBLK 128

typedef unsigned short u16;
typedef __attribute__((ext_vector_type(8))) __bf16 bf16x8_t;
typedef __attribute__((ext_vector_type(4))) float f32x4_t;

#define LOG2E 1.44269504f

static __device__ __forceinline__ u16 f2bf(float f) {
  union { float f; uint32_t u; } v; v.f = f;
  uint32_t r = v.u + 0x7FFFu + ((v.u >> 16) & 1u);
  return (u16)(r >> 16);
}

static __device__ __forceinline__ uint32_t packbf2(float a, float b) {
  __hip_bfloat162 h2 = __float22bfloat162_rn(make_float2(a, b));
  union { __hip_bfloat162 hh; uint32_t u; } cvt; cvt.hh = h2;
  return cvt.u;
}

// raw v_exp_f32: computes 2^x in ONE instruction (no libm slow path, no ln2 mul)
static __device__ __forceinline__ float exp2_raw(float x) {
  float r;
  asm("v_exp_f32 %0, %1" : "=v"(r) : "v"(x));
  return r;
}

// async global->LDS, 16B per lane. LDS dest must be wave-uniform base + lane*16.
static __device__ __forceinline__ void async_copy16(const void* g, void* l) {
  __builtin_amdgcn_global_load_lds((const __attribute__((address_space(1))) void*)g,
                                   (__attribute__((address_space(3))) void*)l, 16, 0, 0);
}

// ---------------- fused prep: logf (blocks 0..4095) + weight transpose (blocks 4096..5119) ----------------
__global__ void prep_kernel(const float* __restrict__ x, const float* __restrict__ Wf,
                            float* __restrict__ lf, u16* __restrict__ xb,
                            const float* __restrict__ W0, const float* __restrict__ W1,
                            const float* __restrict__ W2, const float* __restrict__ W3,
                            u16* __restrict__ Wt) {
  __shared__ float xs[DD];
  __shared__ float part[16][17];
  __shared__ float tile[64][65];
  int t = threadIdx.x;  // 256
  if (blockIdx.x < 4096) {
    int row = blockIdx.x;   // b*N + n
    float4 v = *(const float4*)&x[(size_t)row * DD + t * 4];
    *(float4*)&xs[t * 4] = v;
    ushort4 o;
    o.x = f2bf(v.x); o.y = f2bf(v.y); o.z = f2bf(v.z); o.w = f2bf(v.w);
    *(ushort4*)&xb[(size_t)row * DD + t * 4] = o;
    __syncthreads();
    int h = t & 15, chunk = t >> 4;
    float s = 0.f;
#pragma unroll 8
    for (int e = 0; e < 64; e++)
      s += xs[chunk * 64 + e] * Wf[(chunk * 64 + e) * HH + h];
    part[chunk][h] = s;
    __syncthreads();
    if (t < 16) {
      float z = 0.f;
#pragma unroll
      for (int i = 0; i < 16; i++) z += part[i][t];
      float ls = fminf(z, 0.f) - log1pf(__expf(-fabsf(z)));
      int b = row >> 11, n = row & (NN - 1);
      lf[(b * HH + t) * NN + n] = ls;
    }
  } else {
    int bid = blockIdx.x - 4096;
    int wq = bid >> 8;  // which weight
    const float* W = wq == 0 ? W0 : wq == 1 ? W1 : wq == 2 ? W2 : W3;
    u16* out = Wt + (size_t)wq * DD * DD;
    int bx = bid & 15;          // n tile
    int by = (bid >> 4) & 15;   // k tile
    int c = t & 63, r4 = t >> 6;
#pragma unroll
    for (int i = 0; i < 16; i++) {
      int row = i * 4 + r4;
      tile[row][c] = W[(by * 64 + row) * DD + bx * 64 + c];
    }
    __syncthreads();
#pragma unroll
    for (int i = 0; i < 16; i++) {
      int row = i * 4 + r4;
      out[(bx * 64 + row) * DD + by * 64 + c] = f2bf(tile[c][row]);
    }
  }
}

// ---------------- cumsum over n per (b,h): float4/lane; OUTPUT PRE-SCALED by log2(e) ----------------
__global__ void cumsum_kernel(const float* __restrict__ lf, float* __restrict__ c) {
  int bh = blockIdx.x;
  int lane = threadIdx.x;  // 64
  const float* in = lf + bh * NN;
  float* out = c + bh * NN;
  float carry = 0.f;
  for (int t0 = 0; t0 < NN; t0 += 256) {
    float4 v = *(const float4*)&in[t0 + lane * 4];
    float s1 = v.x + v.y, s2 = s1 + v.z, s3 = s2 + v.w;
    float incl = s3;
#pragma unroll
    for (int off = 1; off < 64; off <<= 1) {
      float u = __shfl_up(incl, off, 64);
      if (lane >= off) incl += u;
    }
    float excl = incl - s3 + carry;
    float4 o;
    o.x = (excl + v.x) * LOG2E; o.y = (excl + s1) * LOG2E;
    o.z = (excl + s2) * LOG2E; o.w = (excl + s3) * LOG2E;
    *(float4*)&out[t0 + lane * 4] = o;
    carry = __shfl(incl, 63, 64) + carry;
  }
}

// ---------------- QKV GEMM 128x128 tile, BK=64, swizzled LDS, 512 threads (8 waves, 2x4) ----------------
// Wt is [3072][1024]; Q/K -> [bh][n][hd] bf16; V -> [bh][hd][n] bf16 (fused transpose)
__global__ __launch_bounds__(512, 4) void gemm_kernel(const u16* __restrict__ A,
                                                      const u16* __restrict__ Wt,
                                                      u16* __restrict__ oQ, u16* __restrict__ oK,
                                                      u16* __restrict__ oV) {
  __shared__ u16 Als[128 * 64];
  __shared__ u16 Bls[128 * 64];
  int m0 = blockIdx.y * 128, n0 = blockIdx.x * 128;
  int tid = threadIdx.x;
  int lane = tid & 63, w = tid >> 6;   // 8 waves
  int wm = w >> 2, wn = w & 3;         // 2 x 4 wave grid: 64 rows x 32 cols each
  int lr = lane & 15, lg = lane >> 4;

  const u16* gA[2]; const u16* gB[2]; u16* lA[2]; u16* lB[2];
#pragma unroll
  for (int j = 0; j < 2; j++) {
    int s = tid + j * 512;
    int row = s >> 3, ch = s & 7;
    int scol = (ch ^ (row & 7)) * 8;
    gA[j] = &A [(size_t)(m0 + row) * DD + scol];
    gB[j] = &Wt[(size_t)(n0 + row) * DD + scol];
    lA[j] = &Als[s * 8];
    lB[j] = &Bls[s * 8];
  }

  f32x4_t acc[4][2];
#pragma unroll
  for (int i = 0; i < 4; i++)
#pragma unroll
    for (int j = 0; j < 2; j++) acc[i][j] = (f32x4_t){0.f, 0.f, 0.f, 0.f};

  for (int kt = 0; kt < DD; kt += 64) {
    __syncthreads();
#pragma unroll
    for (int j = 0; j < 2; j++) {
      async_copy16(gA[j] + kt, lA[j]);
      async_copy16(gB[j] + kt, lB[j]);
    }
    __syncthreads();
#pragma unroll
    for (int kk = 0; kk < 2; kk++) {
      bf16x8_t af[4], bfv[2];
#pragma unroll
      for (int mi = 0; mi < 4; mi++) {
        int row = wm * 64 + mi * 16 + lr;
        int boff = (row * 128 + kk * 64 + lg * 16) ^ ((row & 7) << 4);
        af[mi] = *(const bf16x8_t*)((const char*)Als + boff);
      }
#pragma unroll
      for (int ni = 0; ni < 2; ni++) {
        int row = wn * 32 + ni * 16 + lr;
        int boff = (row * 128 + kk * 64 + lg * 16) ^ ((row & 7) << 4);
        bfv[ni] = *(const bf16x8_t*)((const char*)Bls + boff);
      }
#pragma unroll
      for (int mi = 0; mi < 4; mi++)
#pragma unroll
        for (int ni = 0; ni < 2; ni++)
          acc[mi][ni] = __builtin_amdgcn_mfma_f32_16x16x32_bf16(af[mi], bfv[ni], acc[mi][ni], 0, 0, 0);
    }
  }

  int which = n0 >> 10;
  int nl0 = n0 & 1023;
  if (which == 2) {
    // V: write transposed [bh][hd][n] -- 4 consecutive n per thread = packed 8B store
#pragma unroll
    for (int mi = 0; mi < 4; mi++)
#pragma unroll
      for (int ni = 0; ni < 2; ni++) {
        int gcol = nl0 + wn * 32 + ni * 16 + lr;
        int h = gcol >> 6, hd = gcol & 63;
        int grow0 = m0 + wm * 64 + mi * 16 + lg * 4;
        int b = grow0 >> 11, n = grow0 & (NN - 1);
        ushort4 o4;
        o4.x = f2bf(acc[mi][ni][0]);
        o4.y = f2bf(acc[mi][ni][1]);
        o4.z = f2bf(acc[mi][ni][2]);
        o4.w = f2bf(acc[mi][ni][3]);
        *(ushort4*)&oV[((size_t)(b * HH + h) * HDD + hd) * NN + n] = o4;
      }
  } else {
    u16* outp = which == 0 ? oQ : oK;
#pragma unroll
    for (int mi = 0; mi < 4; mi++)
#pragma unroll
      for (int ni = 0; ni < 2; ni++) {
        int gcol = nl0 + wn * 32 + ni * 16 + lr;
        int h = gcol >> 6, hd = gcol & 63;
#pragma unroll
        for (int r = 0; r < 4; r++) {
          int grow = m0 + wm * 64 + mi * 16 + lg * 4 + r;
          int b = grow >> 11, n = grow & (NN - 1);
          outp[((size_t)(b * HH + h) * NN + n) * HDD + hd] = f2bf(acc[mi][ni][r]);
        }
      }
  }
}

// ---------------- out GEMM 128x64 tile, BK=64, grid 512 = 2 blocks/CU (overlap barrier stalls) ----------------
__global__ __launch_bounds__(512, 4) void gemm_out_kernel(const u16* __restrict__ A,
                                                          const u16* __restrict__ Wt,
                                                          float* __restrict__ oF) {
  __shared__ u16 Als[128 * 64];
  __shared__ u16 Bls[64 * 64];
  int m0 = blockIdx.y * 128, n0 = blockIdx.x * 64;
  int tid = threadIdx.x;
  int lane = tid & 63, w = tid >> 6;   // 8 waves
  int wm = w >> 2, wn = w & 3;         // 2 x 4 wave grid: 64 rows x 16 cols each
  int lr = lane & 15, lg = lane >> 4;

  const u16* gA[2]; u16* lA[2];
#pragma unroll
  for (int j = 0; j < 2; j++) {
    int s = tid + j * 512;
    int row = s >> 3, ch = s & 7;
    int scol = (ch ^ (row & 7)) * 8;
    gA[j] = &A[(size_t)(m0 + row) * DD + scol];
    lA[j] = &Als[s * 8];
  }
  int rowb = tid >> 3, chb = tid & 7;
  const u16* gB = &Wt[(size_t)(n0 + rowb) * DD + ((chb ^ (rowb & 7)) * 8)];
  u16* lB = &Bls[tid * 8];

  f32x4_t acc[4];
#pragma unroll
  for (int i = 0; i < 4; i++) acc[i] = (f32x4_t){0.f, 0.f, 0.f, 0.f};

  for (int kt = 0; kt < DD; kt += 64) {
    __syncthreads();
#pragma unroll
    for (int j = 0; j < 2; j++) async_copy16(gA[j] + kt, lA[j]);
    async_copy16(gB + kt, lB);
    __syncthreads();
#pragma unroll
    for (int kk = 0; kk < 2; kk++) {
      bf16x8_t af[4], bf1;
#pragma unroll
      for (int mi = 0; mi < 4; mi++) {
        int row = wm * 64 + mi * 16 + lr;
        int boff = (row * 128 + kk * 64 + lg * 16) ^ ((row & 7) << 4);
        af[mi] = *(const bf16x8_t*)((const char*)Als + boff);
      }
      {
        int row = wn * 16 + lr;
        int boff = (row * 128 + kk * 64 + lg * 16) ^ ((row & 7) << 4);
        bf1 = *(const bf16x8_t*)((const char*)Bls + boff);
      }
#pragma unroll
      for (int mi = 0; mi < 4; mi++)
        acc[mi] = __builtin_amdgcn_mfma_f32_16x16x32_bf16(af[mi], bf1, acc[mi], 0, 0, 0);
    }
  }

#pragma unroll
  for (int mi = 0; mi < 4; mi++) {
    int gcol = n0 + wn * 16 + lr;
#pragma unroll
    for (int r = 0; r < 4; r++) {
      int grow = m0 + wm * 64 + mi * 16 + lg * 4 + r;
      oF[(size_t)grow * DD + gcol] = acc[mi][r];
    }
  }
}

// ---------------- flash attention: KVBLK=128 (half the barriers), raw v_exp softmax ----------------
// Sequential paired q-tiles (31-p then p); per tile nt = (tile>>1)+1 kv tiles of 128
// (UNIFORM pair total = 17 iters for every p). Even tiles' last kv tile overhangs <=64
// cols past the diagonal -- all reads in-bounds (<=2048), masked via jj>iq AFTER exp
// (garbage-safe). Double-buffered global_load_lds staging (8x16B/thread per tile);
// exp2-domain softmax: cw pre-scaled by log2e, SCL=0.125*log2e, raw v_exp_f32 (r13
// lesson: libm exp2f has slow-path VALU; the raw instruction IS 2^x).
__global__ __launch_bounds__(256) void attn_kernel(const u16* __restrict__ Q,
                                                   const u16* __restrict__ K,
                                                   const u16* __restrict__ Vt,
                                                   const float* __restrict__ cw,
                                                   u16* __restrict__ O) {
  __shared__ u16 Kls[2][KVBLK * 64];   // [128 kv rows][64 hd], 16KB each
  __shared__ u16 Vls[2][64 * KVBLK];   // [64 hd][128 kv], 16KB each
  int flat = blockIdx.y * gridDim.x + blockIdx.x;  // grid (16, 32) = 512
  int swz = (flat & 7) * 64 + (flat >> 3);         // bijective, bh-contiguous per XCD
  int pidx = swz & 15, bh = swz >> 4;
  int tid = threadIdx.x;
  int lane = tid & 63, w = tid >> 6;
  int lr = lane & 15, lg = lane >> 4;
  const u16* Qh = Q + (size_t)bh * NN * HDD;
  const u16* Kh = K + (size_t)bh * NN * HDD;
  const u16* Vh = Vt + (size_t)bh * HDD * NN;
  const float* ch = cw + bh * NN;   // pre-scaled by log2e
  int b = bh >> 4, h = bh & 15;

  const float SCL = 0.125f * LOG2E;

  // staging: K tile = 1024 slots of 16B (row=s>>3, chunk=s&7); V tile = 1024 slots
  // (row=s>>4, chunk=s&15). Thread stages slots tid+j*256, j=0..3. LDS linear at
  // slot*16B; swizzle folded into SOURCE chunk: chunk ^ (row&7).
  const u16* gk[4]; const u16* gv[4];
#pragma unroll
  for (int j = 0; j < 4; j++) {
    int s = tid + j * 256;
    int kr = s >> 3, kc = s & 7;
    gk[j] = &Kh[(size_t)kr * HDD + ((kc ^ (kr & 7)) * 8)];
    int vr = s >> 4, vc = s & 15;
    gv[j] = &Vh[(size_t)vr * NN + ((vc ^ (vr & 7)) * 8)];
  }

  for (int which = 0; which < 2; which++) {
    int tile = which == 0 ? (31 - pidx) : pidx;
    int qb = tile * QBLK + w * 16;
    int iq = qb + lr;  // this lane's q-row

    bf16x8_t qf[2];
#pragma unroll
    for (int s = 0; s < 2; s++)
      qf[s] = *(const bf16x8_t*)&Qh[(size_t)iq * HDD + s * 32 + lg * 8];
    float cq = ch[iq];

    float lsum = 0.f;
    f32x4_t oacc[4];
#pragma unroll
    for (int fn = 0; fn < 4; fn++) oacc[fn] = (f32x4_t){0.f, 0.f, 0.f, 0.f};

    int nt = (tile >> 1) + 1;

    // prologue: stage kv tile 0 into buffer 0
#pragma unroll
    for (int j = 0; j < 4; j++) {
      int s = tid + j * 256;
      async_copy16(gk[j], &Kls[0][s * 8]);
      async_copy16(gv[j], &Vls[0][s * 8]);
    }
    __syncthreads();

    int cur = 0;
    for (int kvt = 0; kvt < nt; kvt++) {
      // stage next tile into the other buffer BEFORE computing this one
      if (kvt + 1 < nt) {
        size_t kvn = (size_t)(kvt + 1) * KVBLK;
        int nb = cur ^ 1;
#pragma unroll
        for (int j = 0; j < 4; j++) {
          int s = tid + j * 256;
          async_copy16(gk[j] + kvn * HDD, &Kls[nb][s * 8]);
          async_copy16(gv[j] + kvn, &Vls[nb][s * 8]);
        }
      }
      int kv0 = kvt * KVBLK;
      const u16* Kb = Kls[cur];
      const u16* Vb = Vls[cur];
      float4 ckv[8];
#pragma unroll
      for (int f = 0; f < 8; f++)
        ckv[f] = *(const float4*)&ch[kv0 + f * 16 + lg * 4];

      // S^T = K . Q^T : lane holds col i=lr, rows j = kv0 + f*16 + lg*4 + r  (f=0..7)
      f32x4_t sacc[8];
#pragma unroll
      for (int f = 0; f < 8; f++) sacc[f] = (f32x4_t){0.f, 0.f, 0.f, 0.f};
      __builtin_amdgcn_s_setprio(1);
#pragma unroll
      for (int f = 0; f < 8; f++) {
        int row = f * 16 + lr;
#pragma unroll
        for (int s = 0; s < 2; s++) {
          int boff = (row * 128 + s * 64 + lg * 16) ^ ((row & 7) << 4);
          bf16x8_t kf = *(const bf16x8_t*)((const char*)Kb + boff);
          sacc[f] = __builtin_amdgcn_mfma_f32_16x16x32_bf16(kf, qf[s], sacc[f], 0, 0, 0);
        }
      }
      __builtin_amdgcn_s_setprio(0);

      // fixed-max softmax, exp2 domain: e = 2^(s*SCL + cq - ck); mask AFTER exp
      bool diag = (kvt == nt - 1);
      float pv[8][4];
#pragma unroll
      for (int f = 0; f < 8; f++) {
        const float* ckp = &ckv[f].x;
#pragma unroll
        for (int r = 0; r < 4; r++) {
          float val = fmaf(sacc[f][r], SCL, cq - ckp[r]);
          float e = exp2_raw(val);
          if (diag && (kv0 + f * 16 + lg * 4 + r) > iq) e = 0.f;
          pv[f][r] = e; lsum += e;
        }
      }

      // pack P quarters to bf16 + permlane network -> 4 B-fragments (s covers kv cols 32s..32s+31)
      bf16x8_t pa[4];
#pragma unroll
      for (int s = 0; s < 4; s++) {
        uint32_t x0 = packbf2(pv[2 * s][0], pv[2 * s][1]);
        uint32_t x1 = packbf2(pv[2 * s][2], pv[2 * s][3]);
        uint32_t y0 = packbf2(pv[2 * s + 1][0], pv[2 * s + 1][1]);
        uint32_t y1 = packbf2(pv[2 * s + 1][2], pv[2 * s + 1][3]);
        asm volatile("v_permlane32_swap_b32 %0, %1" : "+v"(x0), "+v"(y0));
        asm volatile("v_permlane32_swap_b32 %0, %1" : "+v"(x1), "+v"(y1));
        asm volatile("v_permlane16_swap_b32 %0, %1" : "+v"(x0), "+v"(y0));
        asm volatile("v_permlane16_swap_b32 %0, %1" : "+v"(x1), "+v"(y1));
        union { uint32_t u[4]; bf16x8_t v; } pk;
        pk.u[0] = x0; pk.u[1] = x1; pk.u[2] = y0; pk.u[3] = y1;
        pa[s] = pk.v;
      }

      // O^T += V^T . P  (V^T rows are 256B; swizzle on within-row offset only)
      __builtin_amdgcn_s_setprio(1);
#pragma unroll
      for (int fn = 0; fn < 4; fn++) {
        int row = fn * 16 + lr;
#pragma unroll
        for (int s = 0; s < 4; s++) {
          int boff = row * 256 + ((s * 64 + lg * 16) ^ ((row & 7) << 4));
          bf16x8_t vf = *(const bf16x8_t*)((const char*)Vb + boff);
          oacc[fn] = __builtin_amdgcn_mfma_f32_16x16x32_bf16(vf, pa[s], oacc[fn], 0, 0, 0);
        }
      }
      __builtin_amdgcn_s_setprio(0);
      __syncthreads();
      cur ^= 1;
    }

    // l-reduce over the 4 lanes sharing lr
    lsum += __shfl_xor(lsum, 16, 64);
    lsum += __shfl_xor(lsum, 32, 64);
    float rinv = 1.0f / lsum;

    // output: lane's q-row iq, hd = fn*16 + lg*4 + r -> packed 8B stores
    u16* orow = O + ((size_t)(b * NN + iq)) * DD + h * HDD;
#pragma unroll
    for (int fn = 0; fn < 4; fn++) {
      ushort4 o4;
      o4.x = f2bf(oacc[fn][0] * rinv);
      o4.y = f2bf(oacc[fn][1] * rinv);
      o4.z = f2bf(oacc[fn][2] * rinv);
      o4.w = f2bf(oacc[fn][3] * rinv);
      *(ushort4*)&orow[fn * 16 + lg * 4] = o4;
    }
  }
}

extern "C" void kernel_launch(void* const* d_in, const int* in_sizes, int n_in,
                              void* d_out, int out_size, void* d_ws, size_t ws_size,
                              hipStream_t stream) {
  const float* x  = (const float*)d_in[0];
  const float* Wq = (const float*)d_in[1];
  const float* Wk = (const float*)d_in[2];
  const float* Wv = (const float*)d_in[3];
  const float* Wo = (const float*)d_in[4];
  const float* Wf = (const float*)d_in[5];
  float* out = (float*)d_out;
  char* ws = (char*)d_ws;
  const size_t MB = 1024 * 1024;
  u16* x_bf  = (u16*)(ws + 0);        // 8 MB
  u16* WqkvT = (u16*)(ws + 8 * MB);   // 6 MB: WqT | WkT | WvT contiguous [3072][1024]; WoT follows
  u16* Qw    = (u16*)(ws + 16 * MB);  // 8 MB [bh][n][hd]
  u16* Kw    = (u16*)(ws + 24 * MB);  // 8 MB
  u16* Vw    = (u16*)(ws + 32 * MB);  // 8 MB [bh][hd][n] (written transposed by gemm)
  u16* Ow    = (u16*)(ws + 40 * MB);  // 8 MB [b n d]
  float* lf  = (float*)(ws + 48 * MB);            // 256 KB
  float* cwp = (float*)(ws + 48 * MB + 262144);   // 256 KB (pre-scaled by log2e)

  // fused prep: logf+cast (4096 blocks) || weight transpose (1024 blocks)
  prep_kernel<<<5120, 256, 0, stream>>>(x, Wf, lf, x_bf, Wq, Wk, Wv, Wo, WqkvT);
  cumsum_kernel<<<32, 64, 0, stream>>>(lf, cwp);
  // fused QKV GEMM: N = 3072; V written directly transposed
  gemm_kernel<<<dim3(24, 32), 512, 0, stream>>>(x_bf, WqkvT, Qw, Kw, Vw);
  attn_kernel<<<dim3(16, 32), 256, 0, stream>>>(Qw, Kw, Vw, cwp, Ow);
  gemm_out_kernel<<<dim3(16, 32), 512, 0, stream>>>(Ow, WqkvT + (size_t)3 * DD * DD, out);
}